// Round 7
// baseline (5787.676 us; speedup 1.0000x reference)
//
#include <hip/hip_runtime.h>
#include <hip/hip_bf16.h>

typedef __bf16 bf16x8 __attribute__((ext_vector_type(8)));
typedef float f32x4 __attribute__((ext_vector_type(4)));
typedef unsigned long long u64;

#define DEV static __device__ __forceinline__

constexpr int Bq = 32, Sq = 128, Tq = 64, Eq = 256, Hq = 512, Vq = 32000;
constexpr int G4 = 2048;          // 4*H
constexpr int TD = 63;            // decode steps (T-1)
constexpr int KOUT = 1280;        // 2H + E
constexpr float SQRTE = 16.0f;    // sqrt(256)

DEV float sigf(float x) { return 1.0f / (1.0f + __expf(-x)); }
DEV float tanh_fast(float x) {
    float ax = fabsf(x);
    float t = __expf(-2.f * ax);
    float r = (1.f - t) / (1.f + t);
    return x < 0.f ? -r : r;
}
DEV float tanh_c(float x) {
    float xc = fminf(fmaxf(x, -15.f), 15.f);
    float t = __expf(2.f * xc);
    return (t - 1.f) / (t + 1.f);
}

// ---- coherent (agent-scope) access helpers ----
DEV u64 ldc(const u64* p) {
    return __hip_atomic_load(p, __ATOMIC_RELAXED, __HIP_MEMORY_SCOPE_AGENT);
}
DEV unsigned ldc32(const unsigned* p) {
    return __hip_atomic_load(p, __ATOMIC_RELAXED, __HIP_MEMORY_SCOPE_AGENT);
}
DEV void stc(u64* p, u64 v) {
    __hip_atomic_store(p, v, __ATOMIC_RELAXED, __HIP_MEMORY_SCOPE_AGENT);
}
DEV void stc32(unsigned* p, unsigned v) {
    __hip_atomic_store(p, v, __ATOMIC_RELAXED, __HIP_MEMORY_SCOPE_AGENT);
}
DEV unsigned short bfbits(float f) {
    __bf16 h = (__bf16)f;
    return __builtin_bit_cast(unsigned short, h);
}
DEV float bf2f(unsigned short u) {
    __bf16 h = __builtin_bit_cast(__bf16, u);
    return (float)h;
}
DEV u64 pack4bf(float a, float b, float c, float d) {
    return (u64)bfbits(a) | ((u64)bfbits(b) << 16) |
           ((u64)bfbits(c) << 32) | ((u64)bfbits(d) << 48);
}
DEV u64 pack2f(float a, float b) {
    return (u64)__float_as_uint(a) | ((u64)__float_as_uint(b) << 32);
}

// ---- contention-free global barrier: per-block padded flags, monotone epoch ----
DEV void gbar(unsigned* flags, int nblk, unsigned epoch) {
    __syncthreads();
    if (threadIdx.x < 64) {
        if (threadIdx.x == 0) {
            asm volatile("s_waitcnt vmcnt(0)" ::: "memory");
            stc32(flags + blockIdx.x * 32, epoch);
        }
        int lane = threadIdx.x;
        for (;;) {
            unsigned v0 = (lane < nblk) ? ldc32(flags + lane * 32) : epoch;
            unsigned v1 = (lane + 64 < nblk) ? ldc32(flags + (lane + 64) * 32) : epoch;
            if (__all((int)((v0 >= epoch) && (v1 >= epoch)))) break;
            __builtin_amdgcn_s_sleep(1);
        }
    }
    __syncthreads();
}

// ============ embeddings (bf16 out) ============
__global__ __launch_bounds__(256) void k_embed_src(const int* __restrict__ tok,
                                                   const float* __restrict__ emb,
                                                   __hip_bfloat16* __restrict__ x)
{
    int idx = blockIdx.x * 256 + threadIdx.x;
    int e = idx & (Eq - 1);
    int r = idx >> 8;
    int b = r & 31, t = r >> 5;
    x[idx] = __float2bfloat16(emb[(size_t)tok[b * Sq + t] * Eq + e] * SQRTE);
}

__global__ __launch_bounds__(256) void k_embed_tgt(const int* __restrict__ tok,
                                                   const float* __restrict__ emb,
                                                   __hip_bfloat16* __restrict__ embt,
                                                   __hip_bfloat16* __restrict__ Xout)
{
    int idx = blockIdx.x * 256 + threadIdx.x;
    int e = idx & (Eq - 1);
    int r = idx >> 8;
    int b = r & 31, t = r >> 5;
    float v = fmaxf(0.f, emb[(size_t)tok[b * Tq + t] * Eq + e] * SQRTE);
    embt[idx] = __float2bfloat16(v);
    Xout[(size_t)r * KOUT + 1024 + e] = __float2bfloat16(v);
}

// ============ transpose + cast W (K x N) -> Wt (N x K) bf16 ============
__global__ __launch_bounds__(256) void k_transpose_bf16(const float* __restrict__ W,
                                                        __hip_bfloat16* __restrict__ Wt,
                                                        int K, int N)
{
    __shared__ float tile[32][33];
    int nb = blockIdx.x * 32, kb = blockIdx.y * 32;
    int c = threadIdx.x & 31, r4 = threadIdx.x >> 5;
    for (int i = 0; i < 32; i += 8)
        tile[r4 + i][c] = W[(size_t)(kb + r4 + i) * N + nb + c];
    __syncthreads();
    for (int i = 0; i < 32; i += 8) {
        int rr = r4 + i;
        Wt[(size_t)(nb + rr) * K + kb + c] = __float2bfloat16(tile[c][rr]);
    }
}

// ============ MFMA recurrent helpers (K=512, A=32x512 in LDS, swizzled) ============
DEV void stage_coh(const u64* src, __bf16* As) {
    int tx = threadIdx.x;
#pragma unroll
    for (int p = 0; p < 8; ++p) {
        int c = tx + p * 256;
        int row = c >> 6, kc = c & 63;
        u64 v0 = ldc(src + c * 2);
        u64 v1 = ldc(src + c * 2 + 1);
        int kd = kc ^ (row & 7);
        *(u64*)(As + row * 512 + kd * 8) = v0;
        *(u64*)(As + row * 512 + kd * 8 + 4) = v1;
    }
}

DEV void mfma_pass(const __bf16* As, const unsigned short* BT, int colB,
                   int kg, int fr, f32x4* acc) {
    const unsigned short* bp = BT + (size_t)colB * 512 + kg * 8;
    int f7 = fr & 7;
#pragma unroll
    for (int k0 = 0; k0 < 512; k0 += 32) {
        int cidx = ((k0 >> 3) | kg) ^ f7;
        bf16x8 bfv = *(const bf16x8*)(bp + k0);
        bf16x8 af0 = *(const bf16x8*)(As + fr * 512 + cidx * 8);
        bf16x8 af1 = *(const bf16x8*)(As + (16 + fr) * 512 + cidx * 8);
        acc[0] = __builtin_amdgcn_mfma_f32_16x16x32_bf16(af0, bfv, acc[0], 0, 0, 0);
        acc[1] = __builtin_amdgcn_mfma_f32_16x16x32_bf16(af1, bfv, acc[1], 0, 0, 0);
    }
}

// gates GEMM into gbuf (aliases As0 after sync). Waves = gate index.
DEV void mfma_gates(const __bf16* As0, const __bf16* As1,
                    const __hip_bfloat16* B0T, const __hip_bfloat16* B1T,
                    int j0, float* gbuf)
{
    int tx = threadIdx.x, w = tx >> 6, lane = tx & 63;
    int fr = lane & 15, kg = lane >> 4;
    int colB = w * 512 + j0 + fr;
    f32x4 acc[2];
    acc[0] = (f32x4){0.f, 0.f, 0.f, 0.f};
    acc[1] = (f32x4){0.f, 0.f, 0.f, 0.f};
    mfma_pass(As0, (const unsigned short*)B0T, colB, kg, fr, acc);
    if (B1T) mfma_pass(As1, (const unsigned short*)B1T, colB, kg, fr, acc);
    __syncthreads();
    float* gw = gbuf + w * 512;
#pragma unroll
    for (int m = 0; m < 2; ++m)
#pragma unroll
        for (int qd = 0; qd < 4; ++qd)
            gw[(m * 16 + kg * 4 + qd) * 16 + fr] = acc[m][qd];
    __syncthreads();
}

// single h-pass into a global f32 slab (coherent stores; layout [4][32][16] per tile)
DEV void gh_pass(const u64* hsrc, const __hip_bfloat16* WT,
                 float* slab_tile, int j0, __bf16* As0)
{
    stage_coh(hsrc, As0);
    __syncthreads();
    int tx = threadIdx.x, w = tx >> 6, lane = tx & 63;
    int fr = lane & 15, kg = lane >> 4;
    int colB = w * 512 + j0 + fr;
    f32x4 acc[2];
    acc[0] = (f32x4){0.f, 0.f, 0.f, 0.f};
    acc[1] = (f32x4){0.f, 0.f, 0.f, 0.f};
    mfma_pass(As0, (const unsigned short*)WT, colB, kg, fr, acc);
    float* outp = slab_tile + w * 512;
#pragma unroll
    for (int m = 0; m < 2; ++m)
#pragma unroll
        for (int qd = 0; qd < 4; ++qd)
            stc32((unsigned*)(outp + (m * 16 + kg * 4 + qd) * 16 + fr),
                  __float_as_uint(acc[m][qd]));
}

// cell epilogue: LDS gbuf (+ coherent f32 gadd slab) (+ bf16 xpart) (+ f32 bias)
DEV void cell_epi(const float* gbuf, const float* gadd,
                  const __hip_bfloat16* xpart, const float* bias,
                  float* cbuf, u64* hb, u64* hf,
                  __hip_bfloat16* eb, int ebs, int j0)
{
    int tx = threadIdx.x;
    if (tx >= 128) return;
    int b = tx >> 2, jg = tx & 3;
    int jj0 = jg * 4;
    int j = j0 + jj0;
    float g[4][4];
#pragma unroll
    for (int gi = 0; gi < 4; ++gi) {
        int idx = gi * 512 + b * 16 + jj0;
        float4 gv = *(const float4*)(gbuf + idx);
        g[gi][0] = gv.x; g[gi][1] = gv.y; g[gi][2] = gv.z; g[gi][3] = gv.w;
        if (gadd) {
            u64 p0 = ldc((const u64*)gadd + (idx >> 1));
            u64 p1 = ldc((const u64*)gadd + (idx >> 1) + 1);
            g[gi][0] += __uint_as_float((unsigned)(p0 & 0xffffffffu));
            g[gi][1] += __uint_as_float((unsigned)(p0 >> 32));
            g[gi][2] += __uint_as_float((unsigned)(p1 & 0xffffffffu));
            g[gi][3] += __uint_as_float((unsigned)(p1 >> 32));
        }
        if (xpart) {
            u64 xv = *(const u64*)((const unsigned short*)xpart + b * 2048 + gi * 512 + j);
#pragma unroll
            for (int e = 0; e < 4; ++e)
                g[gi][e] += bf2f((unsigned short)(xv >> (16 * e)));
        }
        if (bias) {
            float4 bv = *(const float4*)(bias + gi * 512 + j);
            g[gi][0] += bv.x; g[gi][1] += bv.y; g[gi][2] += bv.z; g[gi][3] += bv.w;
        }
    }
    float4 cv = *(float4*)(cbuf + b * 512 + j);
    float cc[4] = {cv.x, cv.y, cv.z, cv.w};
    float hv[4];
#pragma unroll
    for (int e = 0; e < 4; ++e) {
        float cn = sigf(g[1][e]) * cc[e] + sigf(g[0][e]) * tanh_fast(g[2][e]);
        cc[e] = cn;
        hv[e] = sigf(g[3][e]) * tanh_fast(cn);
    }
    *(float4*)(cbuf + b * 512 + j) = make_float4(cc[0], cc[1], cc[2], cc[3]);
    u64 hpk = pack4bf(hv[0], hv[1], hv[2], hv[3]);
    stc(hb + ((b * 512 + j) >> 2), hpk);
    stc(hf + ((b * 512 + j) >> 1), pack2f(hv[0], hv[1]));
    stc(hf + ((b * 512 + j) >> 1) + 1, pack2f(hv[2], hv[3]));
    if (eb) *(u64*)(eb + (size_t)b * ebs + j) = hpk;
}

// ============ persistent encoder (64 blocks: 0-31 layer0 @t, 32-63 layer1 @t-1) ============
__global__ __launch_bounds__(256) void k_enc_persist(
    const __hip_bfloat16* __restrict__ X0b,
    const __hip_bfloat16* __restrict__ eWhh0T, const __hip_bfloat16* __restrict__ eWih1T,
    const __hip_bfloat16* __restrict__ eWhh1T, const float* __restrict__ eb1,
    __hip_bfloat16* __restrict__ h0b, __hip_bfloat16* __restrict__ h1b,
    float* __restrict__ h0f, float* __restrict__ h1f,
    float* __restrict__ c0, float* __restrict__ c1,
    __hip_bfloat16* __restrict__ ys0b,
    __hip_bfloat16* __restrict__ encb,
    unsigned* __restrict__ flags)
{
    __shared__ __align__(16) char shm[65536];
    __bf16* As0 = (__bf16*)shm;
    __bf16* As1 = (__bf16*)(shm + 32768);
    bool lay1 = blockIdx.x >= 32;
    int j0 = (blockIdx.x & 31) * 16;
    for (int t = 0; t <= 128; ++t) {
        if (!lay1) {
            if (t < 128) {
                stage_coh((const u64*)(h0b + (t & 1) * 16384), As0);
                __syncthreads();
                mfma_gates(As0, nullptr, eWhh0T, nullptr, j0, (float*)As0);
                cell_epi((float*)As0, nullptr, X0b + (size_t)t * 32 * 2048, nullptr,
                         c0, (u64*)(h0b + ((t + 1) & 1) * 16384), (u64*)h0f,
                         nullptr, 0, j0);
                // ys0 coherent write (layer-1 consumes cross-block)
                if (threadIdx.x < 128) {
                    int b = threadIdx.x >> 2, jg = threadIdx.x & 3;
                    int j = j0 + jg * 4;
                    u64 hpk = ldc((const u64*)(h0b + ((t + 1) & 1) * 16384) + ((b * 512 + j) >> 2));
                    stc((u64*)(ys0b + (size_t)t * 16384 + b * 512 + j), hpk);
                }
            }
        } else {
            if (t >= 1) {
                int s = t - 1;
                stage_coh((const u64*)(ys0b + (size_t)s * 16384), As0);
                stage_coh((const u64*)(h1b + (s & 1) * 16384), As1);
                __syncthreads();
                mfma_gates(As0, As1, eWih1T, eWhh1T, j0, (float*)As0);
                cell_epi((float*)As0, nullptr, nullptr, eb1,
                         c1, (u64*)(h1b + ((s + 1) & 1) * 16384), (u64*)h1f,
                         encb + s * 512, 128 * 512, j0);
            }
        }
        gbar(flags, 64, (unsigned)(t + 1));
    }
}

// ============ persistent decoder (96 blocks, 63 steps x 3 phases) ============
__global__ __launch_bounds__(256) void k_dec_persist(
    const __hip_bfloat16* __restrict__ enc_projb, const __hip_bfloat16* __restrict__ enc_outb,
    const int* __restrict__ src_tok, const float* __restrict__ v_w,
    const float* __restrict__ attn_W, const float* __restrict__ attn_b,
    const float* __restrict__ coal_w, const float* __restrict__ coal_b,
    const __hip_bfloat16* __restrict__ dWih0wT, const __hip_bfloat16* __restrict__ dWhh0T,
    const __hip_bfloat16* __restrict__ dWih1T, const __hip_bfloat16* __restrict__ dWhh1T,
    const float* __restrict__ db1, const __hip_bfloat16* __restrict__ Xembb,
    float* __restrict__ h0fd, float* __restrict__ h1fd,
    __hip_bfloat16* __restrict__ h0bd, __hip_bfloat16* __restrict__ h1bd,
    float* __restrict__ c0d, float* __restrict__ c1d,
    __hip_bfloat16* __restrict__ wctxb,
    __hip_bfloat16* __restrict__ Xout,
    float* __restrict__ g0slab, float* __restrict__ g1slab,
    unsigned* __restrict__ flags)
{
    __shared__ __align__(16) char shm[32768];
    __shared__ float rinvs;
    __bf16* As0 = (__bf16*)shm;
    int bid = blockIdx.x, tx = threadIdx.x;
    unsigned bep = 0;

    for (int t = 0; t < TD; ++t) {
        int cur = t & 1, nxt = cur ^ 1;
        __hip_bfloat16* XoutT = Xout + (size_t)t * 32 * KOUT;

        // ---- Phase 1: attention (0-31)  ∥  g0h (32-63)  ∥  g1h (64-95) ----
        if (bid < 32) {
            int b = bid;
            float* q   = (float*)shm;          // 512
            float* aqs = q + 512;              // 512
            float* vws = aqs + 512;            // 512
            float* ws  = vws + 512;            // 128
            const float* hrow = (b < 16) ? (h0fd + cur * 16384 + b * 1024)
                                         : (h1fd + cur * 16384 + (b - 16) * 1024);
            float cw0 = coal_w[0], cw1 = coal_w[1], cb = coal_b[0];
            for (int j = tx; j < 512; j += 256) {
                u64 pv = ldc((const u64*)hrow + j);
                float v0 = __uint_as_float((unsigned)(pv & 0xffffffffu));
                float v1 = __uint_as_float((unsigned)(pv >> 32));
                q[j] = fmaxf(0.f, v0 * cw0 + v1 * cw1 + cb);
            }
            for (int i = tx; i < 512; i += 256) vws[i] = v_w[i];
            __syncthreads();
            // aq[i] = attn_b[i] + sum_j q[j]*Wq[j][i]  — COALESCED f32 reads of attn_W
            float a0 = attn_b[tx], a1 = attn_b[tx + 256];
#pragma unroll 8
            for (int j = 0; j < 512; ++j) {
                float qj = q[j];
                a0 += qj * attn_W[(size_t)j * 512 + tx];
                a1 += qj * attn_W[(size_t)j * 512 + tx + 256];
            }
            aqs[tx] = a0; aqs[tx + 256] = a1;
            __syncthreads();
            // scores: 2 lanes per s, bf16 enc_proj
            int s = tx >> 1, half = tx & 1;
            const unsigned short* epr = (const unsigned short*)enc_projb
                                        + ((size_t)(b * 128 + s)) * 512 + half * 256;
            float s0 = 0.f, s1 = 0.f, s2 = 0.f, s3 = 0.f;
#pragma unroll 4
            for (int ii = 0; ii < 256; ii += 8) {
                bf16x8 f8 = *(const bf16x8*)(epr + ii);
                int ib = half * 256 + ii;
                s0 += tanh_c((float)f8[0] + aqs[ib])     * vws[ib];
                s1 += tanh_c((float)f8[1] + aqs[ib + 1]) * vws[ib + 1];
                s2 += tanh_c((float)f8[2] + aqs[ib + 2]) * vws[ib + 2];
                s3 += tanh_c((float)f8[3] + aqs[ib + 3]) * vws[ib + 3];
                s0 += tanh_c((float)f8[4] + aqs[ib + 4]) * vws[ib + 4];
                s1 += tanh_c((float)f8[5] + aqs[ib + 5]) * vws[ib + 5];
                s2 += tanh_c((float)f8[6] + aqs[ib + 6]) * vws[ib + 6];
                s3 += tanh_c((float)f8[7] + aqs[ib + 7]) * vws[ib + 7];
            }
            float p = (s0 + s1) + (s2 + s3);
            p += __shfl_xor(p, 1, 64);
            if (half == 0)
                ws[s] = (src_tok[b * 128 + s] != 1) ? __expf(p) : 0.f;
            __syncthreads();
            if (tx < 64) {
                float ss = ws[tx] + ws[tx + 64];
#pragma unroll
                for (int o = 32; o > 0; o >>= 1) ss += __shfl_down(ss, o, 64);
                if (tx == 0) rinvs = 1.0f / ss;
            }
            __syncthreads();
            float rinv = rinvs;
            const unsigned short* eo = (const unsigned short*)enc_outb + (size_t)b * 65536;
            int i0 = tx * 2;
            float c0a = 0.f, c1a = 0.f;
#pragma unroll 4
            for (int s2i = 0; s2i < 128; ++s2i) {
                unsigned pk2 = *(const unsigned*)(eo + (size_t)s2i * 512 + i0);
                float wv = ws[s2i];
                c0a += wv * bf2f((unsigned short)(pk2 & 0xffffu));
                c1a += wv * bf2f((unsigned short)(pk2 >> 16));
            }
            c0a *= rinv; c1a *= rinv;
            unsigned pk = (unsigned)bfbits(c0a) | ((unsigned)bfbits(c1a) << 16);
            stc32((unsigned*)wctxb + ((b * 512 + i0) >> 1), pk);
            *((unsigned*)XoutT + (((size_t)b * KOUT + 512 + i0) >> 1)) = pk;
        } else if (bid < 64) {
            int tile = bid - 32;
            gh_pass((const u64*)(h0bd + cur * 16384), dWhh0T,
                    g0slab + tile * 2048, tile * 16, As0);
        } else {
            int tile = bid - 64;
            gh_pass((const u64*)(h1bd + cur * 16384), dWhh1T,
                    g1slab + tile * 2048, tile * 16, As0);
        }
        gbar(flags, 96, ++bep);

        // ---- Phase 2: cell0-finish (blocks 0-31) ----
        if (bid < 32) {
            int j0 = bid * 16;
            stage_coh((const u64*)wctxb, As0);
            __syncthreads();
            mfma_gates(As0, nullptr, dWih0wT, nullptr, j0, (float*)As0);
            cell_epi((float*)As0, g0slab + bid * 2048,
                     Xembb + (size_t)t * 32 * 2048, nullptr,
                     c0d, (u64*)(h0bd + nxt * 16384), (u64*)(h0fd + nxt * 16384),
                     nullptr, 0, j0);
        }
        gbar(flags, 96, ++bep);

        // ---- Phase 3: cell1-finish (blocks 0-31) ----
        if (bid < 32) {
            int j0 = bid * 16;
            stage_coh((const u64*)(h0bd + nxt * 16384), As0);
            __syncthreads();
            mfma_gates(As0, nullptr, dWih1T, nullptr, j0, (float*)As0);
            cell_epi((float*)As0, g1slab + bid * 2048,
                     nullptr, db1,
                     c1d, (u64*)(h1bd + nxt * 16384), (u64*)(h1fd + nxt * 16384),
                     XoutT, KOUT, j0);
        }
        gbar(flags, 96, ++bep);
    }
}

// ============ generic MFMA GEMM: C(MxN) = A(MxK)bf16 @ BT(NxK)bf16 + bias ============
__global__ __launch_bounds__(256) void k_mfma(
    const __hip_bfloat16* __restrict__ A, const __hip_bfloat16* __restrict__ BT,
    const float* __restrict__ bias, float* __restrict__ Cf,
    __hip_bfloat16* __restrict__ Cb, int M, int N, int K)
{
    __shared__ __bf16 As[128][72];
    __shared__ __bf16 Bs[128][72];
    const unsigned short* Aw = (const unsigned short*)A;
    const unsigned short* Bw = (const unsigned short*)BT;
    int n0 = blockIdx.x * 128, m0 = blockIdx.y * 128;
    int tx = threadIdx.x;
    int w = tx >> 6, lane = tx & 63;
    int wm = (w >> 1) * 64, wn = (w & 1) * 64;
    int fr = lane & 15, kg = lane >> 4;
    f32x4 acc[4][4];
#pragma unroll
    for (int mi = 0; mi < 4; mi++)
#pragma unroll
        for (int ni = 0; ni < 4; ni++) acc[mi][ni] = (f32x4){0.f, 0.f, 0.f, 0.f};

    for (int k0 = 0; k0 < K; k0 += 64) {
        __syncthreads();
#pragma unroll
        for (int p = 0; p < 4; p++) {
            int ch = tx + p * 256;
            int r = ch >> 3, cc = (ch & 7) * 8;
            uint4 va = {0u, 0u, 0u, 0u};
            int m = m0 + r;
            if (m < M) va = *(const uint4*)(Aw + (size_t)m * K + k0 + cc);
            *(uint4*)(&As[r][cc]) = va;
            uint4 vb = *(const uint4*)(Bw + (size_t)(n0 + r) * K + k0 + cc);
            *(uint4*)(&Bs[r][cc]) = vb;
        }
        __syncthreads();
#pragma unroll
        for (int kk = 0; kk < 64; kk += 32) {
            bf16x8 af[4], bfv[4];
#pragma unroll
            for (int i = 0; i < 4; i++) {
                af[i]  = *(const bf16x8*)(&As[wm + i * 16 + fr][kk + kg * 8]);
                bfv[i] = *(const bf16x8*)(&Bs[wn + i * 16 + fr][kk + kg * 8]);
            }
#pragma unroll
            for (int mi = 0; mi < 4; mi++)
#pragma unroll
                for (int ni = 0; ni < 4; ni++)
                    acc[mi][ni] = __builtin_amdgcn_mfma_f32_16x16x32_bf16(
                        af[mi], bfv[ni], acc[mi][ni], 0, 0, 0);
        }
    }
#pragma unroll
    for (int ni = 0; ni < 4; ni++) {
        int n = n0 + wn + ni * 16 + fr;
        float bv = bias ? bias[n] : 0.f;
#pragma unroll
        for (int mi = 0; mi < 4; mi++) {
#pragma unroll
            for (int qd = 0; qd < 4; qd++) {
                int R = m0 + wm + mi * 16 + kg * 4 + qd;
                if (R < M) {
                    float v = acc[mi][ni][qd] + bv;
                    if (Cf) Cf[(size_t)R * N + n] = v;
                    else    Cb[(size_t)R * N + n] = __float2bfloat16(v);
                }
            }
        }
    }
}

// ============ small kernels ============
__global__ __launch_bounds__(256) void k_init_dec(
    const float* __restrict__ h0e, const float* __restrict__ h1e,
    const float* __restrict__ c0e, const float* __restrict__ c1e,
    float* __restrict__ h0fd, float* __restrict__ h1fd,
    __hip_bfloat16* __restrict__ h0bd, __hip_bfloat16* __restrict__ h1bd,
    float* __restrict__ c0d, float* __restrict__ c1d)
{
    int idx = blockIdx.x * 256 + threadIdx.x;
    float a = h0e[idx], b = h1e[idx];
    h0fd[idx] = a; h1fd[idx] = b;
    h0bd[idx] = __float2bfloat16(a);
    h1bd[idx] = __float2bfloat16(b);
    c0d[idx] = c0e[idx];
    c1d[idx] = c1e[idx];
}

__global__ __launch_bounds__(256) void k_bos(float* __restrict__ out)
{
    int b = blockIdx.y;
    int i = blockIdx.x * 256 + threadIdx.x;
    out[(size_t)b * (Tq * Vq) + i] = 2.0f;
}

__global__ __launch_bounds__(256) void k_finalize(
    const float* __restrict__ h0f, const float* __restrict__ h1f,
    const float* __restrict__ c0f, const float* __restrict__ c1f,
    float* __restrict__ out)
{
    int idx = blockIdx.x * 256 + threadIdx.x;
    size_t base = (size_t)Bq * Tq * Vq;
    out[base + idx] = h0f[idx];
    out[base + 16384 + idx] = h1f[idx];
    out[base + 32768 + idx] = c0f[idx];
    out[base + 49152 + idx] = c1f[idx];
}

// ============ logits GEMM (scatter epilogue) ============
__global__ __launch_bounds__(256) void k_logits(
    const __hip_bfloat16* __restrict__ A, const __hip_bfloat16* __restrict__ Bt,
    const float* __restrict__ bias, float* __restrict__ out)
{
    __shared__ __bf16 As[128][72];
    __shared__ __bf16 Bs[128][72];
    const unsigned short* Aw = (const unsigned short*)A;
    const unsigned short* Bw = (const unsigned short*)Bt;
    int n0 = blockIdx.x * 128, m0 = blockIdx.y * 128;
    int tx = threadIdx.x;
    int w = tx >> 6, lane = tx & 63;
    int wm = (w >> 1) * 64, wn = (w & 1) * 64;
    int fr = lane & 15, kg = lane >> 4;
    f32x4 acc[4][4];
#pragma unroll
    for (int mi = 0; mi < 4; mi++)
#pragma unroll
        for (int ni = 0; ni < 4; ni++) acc[mi][ni] = (f32x4){0.f, 0.f, 0.f, 0.f};

    for (int k0 = 0; k0 < 1280; k0 += 64) {
        __syncthreads();
#pragma unroll
        for (int p = 0; p < 4; p++) {
            int ch = tx + p * 256;
            int r = ch >> 3, cc = (ch & 7) * 8;
            uint4 va = {0u, 0u, 0u, 0u};
            int m = m0 + r;
            if (m < 2016) va = *(const uint4*)(Aw + (size_t)m * 1280 + k0 + cc);
            *(uint4*)(&As[r][cc]) = va;
            uint4 vb = *(const uint4*)(Bw + (size_t)(n0 + r) * 1280 + k0 + cc);
            *(uint4*)(&Bs[r][cc]) = vb;
        }
        __syncthreads();
#pragma unroll
        for (int kk = 0; kk < 64; kk += 32) {
            bf16x8 af[4], bfv[4];
#pragma unroll
            for (int i = 0; i < 4; i++) {
                af[i]  = *(const bf16x8*)(&As[wm + i * 16 + fr][kk + kg * 8]);
                bfv[i] = *(const bf16x8*)(&Bs[wn + i * 16 + fr][kk + kg * 8]);
            }
#pragma unroll
            for (int mi = 0; mi < 4; mi++)
#pragma unroll
                for (int ni = 0; ni < 4; ni++)
                    acc[mi][ni] = __builtin_amdgcn_mfma_f32_16x16x32_bf16(
                        af[mi], bfv[ni], acc[mi][ni], 0, 0, 0);
        }
    }
#pragma unroll
    for (int ni = 0; ni < 4; ni++) {
        int n = n0 + wn + ni * 16 + fr;
        float bv = bias[n];
#pragma unroll
        for (int mi = 0; mi < 4; mi++) {
#pragma unroll
            for (int qd = 0; qd < 4; qd++) {
                int R = m0 + wm + mi * 16 + kg * 4 + qd;
                if (R < 2016) {
                    int bb = R & 31, ts = R >> 5;
                    out[(size_t)bb * (Tq * Vq) + (size_t)(ts + 1) * Vq + n] =
                        acc[mi][ni][qd] + bv;
                }
            }
        }
    }
}

// ============ launcher ============
extern "C" void kernel_launch(void* const* d_in, const int* in_sizes, int n_in,
                              void* d_out, int out_size, void* d_ws, size_t ws_size,
                              hipStream_t stream)
{
    (void)in_sizes; (void)n_in; (void)out_size; (void)ws_size;
    const int*   src_tok = (const int*)  d_in[0];
    const int*   tgt_tok = (const int*)  d_in[1];
    const float* src_emb = (const float*)d_in[2];
    const float* tgt_emb = (const float*)d_in[3];
    const float* eWih0   = (const float*)d_in[4];
    const float* eWhh0   = (const float*)d_in[5];
    const float* eb0     = (const float*)d_in[6];
    const float* eWih1   = (const float*)d_in[7];
    const float* eWhh1   = (const float*)d_in[8];
    const float* eb1     = (const float*)d_in[9];
    const float* dWih0   = (const float*)d_in[10];
    const float* dWhh0   = (const float*)d_in[11];
    const float* db0     = (const float*)d_in[12];
    const float* dWih1   = (const float*)d_in[13];
    const float* dWhh1   = (const float*)d_in[14];
    const float* db1     = (const float*)d_in[15];
    const float* attn_W  = (const float*)d_in[16];
    const float* attn_b  = (const float*)d_in[17];
    const float* v_w     = (const float*)d_in[18];
    const float* coal_w  = (const float*)d_in[19];
    const float* coal_b  = (const float*)d_in[20];
    const float* out_W   = (const float*)d_in[21];
    const float* out_b   = (const float*)d_in[22];
    float* out = (float*)d_out;

    char* ws = (char*)d_ws;
    size_t off = 0;
    auto alloc = [&](size_t bytes) -> char* {
        char* p = ws + off;
        off += (bytes + 255) & ~(size_t)255;
        return p;
    };
    typedef __hip_bfloat16 BF;
    BF* X0b     = (BF*)alloc(4096ull * 2048 * 2);
    BF* Xembb   = (BF*)alloc(2016ull * 2048 * 2);
    BF* x_srcb  = (BF*)alloc(4096ull * 256 * 2);
    BF* embtb   = (BF*)alloc(2016ull * 256 * 2);
    BF* ys0b    = (BF*)alloc(128ull * 16384 * 2);
    BF* enc_outb  = (BF*)alloc(4096ull * 512 * 2);
    BF* enc_projb = (BF*)alloc(4096ull * 512 * 2);
    BF* wctxb     = (BF*)alloc(16384ull * 2);
    BF* Xout      = (BF*)alloc(2016ull * 1280 * 2);
    BF* Wt        = (BF*)alloc(32000ull * 1280 * 2);
    BF* eWhh0T  = (BF*)alloc(2048ull * 512 * 2);
    BF* eWih1T  = (BF*)alloc(2048ull * 512 * 2);
    BF* eWhh1T  = (BF*)alloc(2048ull * 512 * 2);
    BF* dWih0wT = (BF*)alloc(2048ull * 512 * 2);
    BF* dWhh0T  = (BF*)alloc(2048ull * 512 * 2);
    BF* dWih1T  = (BF*)alloc(2048ull * 512 * 2);
    BF* dWhh1T  = (BF*)alloc(2048ull * 512 * 2);
    BF* eWih0T  = (BF*)alloc(2048ull * 256 * 2);
    BF* dWih0eT = (BF*)alloc(2048ull * 256 * 2);
    BF* WeT     = (BF*)alloc(512ull * 512 * 2);
    BF* h0b_e   = (BF*)alloc(2ull * 16384 * 2);
    BF* h1b_e   = (BF*)alloc(2ull * 16384 * 2);
    float* h0f_e = (float*)alloc(16384ull * 4);
    float* h1f_e = (float*)alloc(16384ull * 4);
    float* c0e   = (float*)alloc(16384ull * 4);
    float* c1e   = (float*)alloc(16384ull * 4);
    float* h0fd  = (float*)alloc(2ull * 16384 * 4);
    float* h1fd  = (float*)alloc(2ull * 16384 * 4);
    BF* h0bd     = (BF*)alloc(2ull * 16384 * 2);
    BF* h1bd     = (BF*)alloc(2ull * 16384 * 2);
    float* c0d   = (float*)alloc(16384ull * 4);
    float* c1d   = (float*)alloc(16384ull * 4);
    float* g0slab = (float*)alloc(32ull * 2048 * 4);
    float* g1slab = (float*)alloc(32ull * 2048 * 4);
    unsigned* encFlags = (unsigned*)alloc(64 * 32 * 4);   // 64 blocks x 128B
    unsigned* decFlags = (unsigned*)alloc(96 * 32 * 4);   // 96 blocks x 128B

    hipMemsetAsync(encFlags, 0, 64 * 32 * 4, stream);
    hipMemsetAsync(decFlags, 0, 96 * 32 * 4, stream);
    hipMemsetAsync(h0b_e, 0, 2 * 16384 * 2, stream);
    hipMemsetAsync(h1b_e, 0, 2 * 16384 * 2, stream);
    hipMemsetAsync(c0e, 0, 16384 * 4, stream);
    hipMemsetAsync(c1e, 0, 16384 * 4, stream);

    // embeddings
    k_embed_src<<<4096, 256, 0, stream>>>(src_tok, src_emb, x_srcb);
    k_embed_tgt<<<2016, 256, 0, stream>>>(tgt_tok, tgt_emb, embtb, Xout);

    // weight transposes (f32 -> bf16, N-major)
    k_transpose_bf16<<<dim3(64, 16), 256, 0, stream>>>(eWhh0, eWhh0T, 512, 2048);
    k_transpose_bf16<<<dim3(64, 16), 256, 0, stream>>>(eWih1, eWih1T, 512, 2048);
    k_transpose_bf16<<<dim3(64, 16), 256, 0, stream>>>(eWhh1, eWhh1T, 512, 2048);
    k_transpose_bf16<<<dim3(64, 16), 256, 0, stream>>>(dWih0 + 256 * 2048, dWih0wT, 512, 2048);
    k_transpose_bf16<<<dim3(64, 16), 256, 0, stream>>>(dWhh0, dWhh0T, 512, 2048);
    k_transpose_bf16<<<dim3(64, 16), 256, 0, stream>>>(dWih1, dWih1T, 512, 2048);
    k_transpose_bf16<<<dim3(64, 16), 256, 0, stream>>>(dWhh1, dWhh1T, 512, 2048);
    k_transpose_bf16<<<dim3(64, 8), 256, 0, stream>>>(eWih0, eWih0T, 256, 2048);
    k_transpose_bf16<<<dim3(64, 8), 256, 0, stream>>>(dWih0, dWih0eT, 256, 2048);
    k_transpose_bf16<<<dim3(16, 16), 256, 0, stream>>>(attn_W + 512 * 512, WeT, 512, 512);
    k_transpose_bf16<<<dim3(1000, 40), 256, 0, stream>>>(out_W, Wt, 1280, 32000);

    // input-side GEMMs (bf16 out)
    k_mfma<<<dim3(16, 32), 256, 0, stream>>>(x_srcb, eWih0T, eb0, nullptr, X0b, 4096, 2048, 256);
    k_mfma<<<dim3(16, 16), 256, 0, stream>>>(embtb, dWih0eT, db0, nullptr, Xembb, 2016, 2048, 256);
    k_bos<<<dim3(125, 32), 256, 0, stream>>>(out);

    // persistent encoder
    k_enc_persist<<<64, 256, 0, stream>>>(X0b, eWhh0T, eWih1T, eWhh1T, eb1,
                                          h0b_e, h1b_e, h0f_e, h1f_e, c0e, c1e,
                                          ys0b, enc_outb, encFlags);

    // enc_proj = enc_out @ We (bf16 out)
    k_mfma<<<dim3(4, 32), 256, 0, stream>>>(enc_outb, WeT, nullptr, nullptr, enc_projb, 4096, 512, 512);

    k_init_dec<<<64, 256, 0, stream>>>(h0f_e, h1f_e, c0e, c1e,
                                       h0fd, h1fd, h0bd, h1bd, c0d, c1d);

    // persistent decoder
    k_dec_persist<<<96, 256, 0, stream>>>(enc_projb, enc_outb, src_tok, v_w,
                                          attn_W, attn_b, coal_w, coal_b,
                                          dWih0wT, dWhh0T, dWih1T, dWhh1T,
                                          db1, Xembb,
                                          h0fd, h1fd, h0bd, h1bd, c0d, c1d,
                                          wctxb, Xout, g0slab, g1slab, decFlags);

    k_finalize<<<64, 256, 0, stream>>>(h0fd + (TD & 1) * 16384, h1fd + (TD & 1) * 16384,
                                       c0d, c1d, out);
    k_logits<<<dim3(250, 16), 256, 0, stream>>>(Xout, Wt, out_b, out);
}

// Round 8
// 5480.097 us; speedup vs baseline: 1.0561x; 1.0561x over previous
//
#include <hip/hip_runtime.h>
#include <hip/hip_bf16.h>

typedef __bf16 bf16x8 __attribute__((ext_vector_type(8)));
typedef float f32x4 __attribute__((ext_vector_type(4)));
typedef unsigned long long u64;

#define DEV static __device__ __forceinline__

constexpr int Bq = 32, Sq = 128, Tq = 64, Eq = 256, Hq = 512, Vq = 32000;
constexpr int G4 = 2048;          // 4*H
constexpr int TD = 63;            // decode steps (T-1)
constexpr int KOUT = 1280;        // 2H + E
constexpr float SQRTE = 16.0f;    // sqrt(256)

DEV float sigf(float x) { return 1.0f / (1.0f + __expf(-x)); }
DEV float tanh_fast(float x) {
    float ax = fabsf(x);
    float t = __expf(-2.f * ax);
    float r = (1.f - t) / (1.f + t);
    return x < 0.f ? -r : r;
}
DEV float tanh_c(float x) {
    float xc = fminf(fmaxf(x, -15.f), 15.f);
    float t = __expf(2.f * xc);
    return (t - 1.f) / (t + 1.f);
}

// ---- coherent (agent-scope) access helpers (encoder only) ----
DEV u64 ldc(const u64* p) {
    return __hip_atomic_load(p, __ATOMIC_RELAXED, __HIP_MEMORY_SCOPE_AGENT);
}
DEV unsigned ldc32(const unsigned* p) {
    return __hip_atomic_load(p, __ATOMIC_RELAXED, __HIP_MEMORY_SCOPE_AGENT);
}
DEV void stc(u64* p, u64 v) {
    __hip_atomic_store(p, v, __ATOMIC_RELAXED, __HIP_MEMORY_SCOPE_AGENT);
}
DEV void stc32(unsigned* p, unsigned v) {
    __hip_atomic_store(p, v, __ATOMIC_RELAXED, __HIP_MEMORY_SCOPE_AGENT);
}
DEV unsigned short bfbits(float f) {
    __bf16 h = (__bf16)f;
    return __builtin_bit_cast(unsigned short, h);
}
DEV float bf2f(unsigned short u) {
    __bf16 h = __builtin_bit_cast(__bf16, u);
    return (float)h;
}
DEV u64 pack4bf(float a, float b, float c, float d) {
    return (u64)bfbits(a) | ((u64)bfbits(b) << 16) |
           ((u64)bfbits(c) << 32) | ((u64)bfbits(d) << 48);
}
DEV u64 pack2f(float a, float b) {
    return (u64)__float_as_uint(a) | ((u64)__float_as_uint(b) << 32);
}

template<bool C> DEV u64 ld64(const u64* p) { return C ? ldc(p) : *p; }
template<bool C> DEV void st64(u64* p, u64 v) { if (C) stc(p, v); else *p = v; }

// ---- contention-free global barrier (encoder persistent kernel only) ----
DEV void gbar(unsigned* flags, int nblk, unsigned epoch) {
    __syncthreads();
    if (threadIdx.x < 64) {
        if (threadIdx.x == 0) {
            asm volatile("s_waitcnt vmcnt(0)" ::: "memory");
            stc32(flags + blockIdx.x * 32, epoch);
        }
        int lane = threadIdx.x;
        for (;;) {
            unsigned v0 = (lane < nblk) ? ldc32(flags + lane * 32) : epoch;
            if (__all((int)(v0 >= epoch))) break;
            __builtin_amdgcn_s_sleep(1);
        }
    }
    __syncthreads();
}

// ============ embeddings (bf16 out) ============
__global__ __launch_bounds__(256) void k_embed_src(const int* __restrict__ tok,
                                                   const float* __restrict__ emb,
                                                   __hip_bfloat16* __restrict__ x)
{
    int idx = blockIdx.x * 256 + threadIdx.x;
    int e = idx & (Eq - 1);
    int r = idx >> 8;
    int b = r & 31, t = r >> 5;
    x[idx] = __float2bfloat16(emb[(size_t)tok[b * Sq + t] * Eq + e] * SQRTE);
}

__global__ __launch_bounds__(256) void k_embed_tgt(const int* __restrict__ tok,
                                                   const float* __restrict__ emb,
                                                   __hip_bfloat16* __restrict__ embt,
                                                   __hip_bfloat16* __restrict__ Xout)
{
    int idx = blockIdx.x * 256 + threadIdx.x;
    int e = idx & (Eq - 1);
    int r = idx >> 8;
    int b = r & 31, t = r >> 5;
    float v = fmaxf(0.f, emb[(size_t)tok[b * Tq + t] * Eq + e] * SQRTE);
    embt[idx] = __float2bfloat16(v);
    Xout[(size_t)r * KOUT + 1024 + e] = __float2bfloat16(v);
}

// ============ transpose + cast W (K x N) -> Wt (N x K) bf16 ============
__global__ __launch_bounds__(256) void k_transpose_bf16(const float* __restrict__ W,
                                                        __hip_bfloat16* __restrict__ Wt,
                                                        int K, int N)
{
    __shared__ float tile[32][33];
    int nb = blockIdx.x * 32, kb = blockIdx.y * 32;
    int c = threadIdx.x & 31, r4 = threadIdx.x >> 5;
    for (int i = 0; i < 32; i += 8)
        tile[r4 + i][c] = W[(size_t)(kb + r4 + i) * N + nb + c];
    __syncthreads();
    for (int i = 0; i < 32; i += 8) {
        int rr = r4 + i;
        Wt[(size_t)(nb + rr) * K + kb + c] = __float2bfloat16(tile[c][rr]);
    }
}

// ============ MFMA recurrent helpers (K=512, A=32x512 in LDS, swizzled) ============
template<bool C>
DEV void stage_a(const u64* src, __bf16* As) {
    int tx = threadIdx.x;
#pragma unroll
    for (int p = 0; p < 8; ++p) {
        int c = tx + p * 256;
        int row = c >> 6, kc = c & 63;
        u64 v0 = ld64<C>(src + c * 2);
        u64 v1 = ld64<C>(src + c * 2 + 1);
        int kd = kc ^ (row & 7);
        *(u64*)(As + row * 512 + kd * 8) = v0;
        *(u64*)(As + row * 512 + kd * 8 + 4) = v1;
    }
}

DEV void mfma_pass(const __bf16* As, const unsigned short* BT, int colB,
                   int kg, int fr, f32x4* acc) {
    const unsigned short* bp = BT + (size_t)colB * 512 + kg * 8;
    int f7 = fr & 7;
#pragma unroll
    for (int k0 = 0; k0 < 512; k0 += 32) {
        int cidx = ((k0 >> 3) | kg) ^ f7;
        bf16x8 bfv = *(const bf16x8*)(bp + k0);
        bf16x8 af0 = *(const bf16x8*)(As + fr * 512 + cidx * 8);
        bf16x8 af1 = *(const bf16x8*)(As + (16 + fr) * 512 + cidx * 8);
        acc[0] = __builtin_amdgcn_mfma_f32_16x16x32_bf16(af0, bfv, acc[0], 0, 0, 0);
        acc[1] = __builtin_amdgcn_mfma_f32_16x16x32_bf16(af1, bfv, acc[1], 0, 0, 0);
    }
}

// gates GEMM into gbuf (aliases As0 after sync). Waves = gate index.
DEV void mfma_gates(const __bf16* As0, const __bf16* As1,
                    const __hip_bfloat16* B0T, const __hip_bfloat16* B1T,
                    int j0, float* gbuf)
{
    int tx = threadIdx.x, w = tx >> 6, lane = tx & 63;
    int fr = lane & 15, kg = lane >> 4;
    int colB = w * 512 + j0 + fr;
    f32x4 acc[2];
    acc[0] = (f32x4){0.f, 0.f, 0.f, 0.f};
    acc[1] = (f32x4){0.f, 0.f, 0.f, 0.f};
    mfma_pass(As0, (const unsigned short*)B0T, colB, kg, fr, acc);
    if (B1T) mfma_pass(As1, (const unsigned short*)B1T, colB, kg, fr, acc);
    __syncthreads();
    float* gw = gbuf + w * 512;
#pragma unroll
    for (int m = 0; m < 2; ++m)
#pragma unroll
        for (int qd = 0; qd < 4; ++qd)
            gw[(m * 16 + kg * 4 + qd) * 16 + fr] = acc[m][qd];
    __syncthreads();
}

// cell epilogue. gadd slab read is always plain (decoder-only feature).
template<bool C>
DEV void cell_epi(const float* gbuf, const float* gadd,
                  const __hip_bfloat16* xpart, const float* bias,
                  float* cbuf, u64* hb, u64* hf,
                  __hip_bfloat16* eb, int ebs, int j0)
{
    int tx = threadIdx.x;
    if (tx >= 128) return;
    int b = tx >> 2, jg = tx & 3;
    int jj0 = jg * 4;
    int j = j0 + jj0;
    float g[4][4];
#pragma unroll
    for (int gi = 0; gi < 4; ++gi) {
        int idx = gi * 512 + b * 16 + jj0;
        float4 gv = *(const float4*)(gbuf + idx);
        g[gi][0] = gv.x; g[gi][1] = gv.y; g[gi][2] = gv.z; g[gi][3] = gv.w;
        if (gadd) {
            float4 ga = *(const float4*)(gadd + idx);
            g[gi][0] += ga.x; g[gi][1] += ga.y; g[gi][2] += ga.z; g[gi][3] += ga.w;
        }
        if (xpart) {
            u64 xv = *(const u64*)((const unsigned short*)xpart + b * 2048 + gi * 512 + j);
#pragma unroll
            for (int e = 0; e < 4; ++e)
                g[gi][e] += bf2f((unsigned short)(xv >> (16 * e)));
        }
        if (bias) {
            float4 bv = *(const float4*)(bias + gi * 512 + j);
            g[gi][0] += bv.x; g[gi][1] += bv.y; g[gi][2] += bv.z; g[gi][3] += bv.w;
        }
    }
    float4 cv = *(float4*)(cbuf + b * 512 + j);
    float cc[4] = {cv.x, cv.y, cv.z, cv.w};
    float hv[4];
#pragma unroll
    for (int e = 0; e < 4; ++e) {
        float cn = sigf(g[1][e]) * cc[e] + sigf(g[0][e]) * tanh_fast(g[2][e]);
        cc[e] = cn;
        hv[e] = sigf(g[3][e]) * tanh_fast(cn);
    }
    *(float4*)(cbuf + b * 512 + j) = make_float4(cc[0], cc[1], cc[2], cc[3]);
    u64 hpk = pack4bf(hv[0], hv[1], hv[2], hv[3]);
    st64<C>(hb + ((b * 512 + j) >> 2), hpk);
    st64<C>(hf + ((b * 512 + j) >> 1), pack2f(hv[0], hv[1]));
    st64<C>(hf + ((b * 512 + j) >> 1) + 1, pack2f(hv[2], hv[3]));
    if (eb) st64<C>((u64*)(eb + (size_t)b * ebs + j), hpk);
}

// ============ persistent encoder (64 blocks: 0-31 layer0 @t, 32-63 layer1 @t-1) ============
__global__ __launch_bounds__(256) void k_enc_persist(
    const __hip_bfloat16* __restrict__ X0b,
    const __hip_bfloat16* __restrict__ eWhh0T, const __hip_bfloat16* __restrict__ eWih1T,
    const __hip_bfloat16* __restrict__ eWhh1T, const float* __restrict__ eb1,
    __hip_bfloat16* __restrict__ h0b, __hip_bfloat16* __restrict__ h1b,
    float* __restrict__ h0f, float* __restrict__ h1f,
    float* __restrict__ c0, float* __restrict__ c1,
    __hip_bfloat16* __restrict__ ys0b,
    __hip_bfloat16* __restrict__ encb,
    unsigned* __restrict__ flags)
{
    __shared__ __align__(16) char shm[65536];
    __bf16* As0 = (__bf16*)shm;
    __bf16* As1 = (__bf16*)(shm + 32768);
    bool lay1 = blockIdx.x >= 32;
    int j0 = (blockIdx.x & 31) * 16;
    for (int t = 0; t <= 128; ++t) {
        if (!lay1) {
            if (t < 128) {
                stage_a<true>((const u64*)(h0b + (t & 1) * 16384), As0);
                __syncthreads();
                mfma_gates(As0, nullptr, eWhh0T, nullptr, j0, (float*)As0);
                cell_epi<true>((float*)As0, nullptr, X0b + (size_t)t * 32 * 2048, nullptr,
                               c0, (u64*)(h0b + ((t + 1) & 1) * 16384), (u64*)h0f,
                               nullptr, 0, j0);
                if (threadIdx.x < 128) {
                    int b = threadIdx.x >> 2, jg = threadIdx.x & 3;
                    int j = j0 + jg * 4;
                    u64 hpk = ldc((const u64*)(h0b + ((t + 1) & 1) * 16384) + ((b * 512 + j) >> 2));
                    stc((u64*)(ys0b + (size_t)t * 16384 + b * 512 + j), hpk);
                }
            }
        } else {
            if (t >= 1) {
                int s = t - 1;
                stage_a<true>((const u64*)(ys0b + (size_t)s * 16384), As0);
                stage_a<true>((const u64*)(h1b + (s & 1) * 16384), As1);
                __syncthreads();
                mfma_gates(As0, As1, eWih1T, eWhh1T, j0, (float*)As0);
                cell_epi<true>((float*)As0, nullptr, nullptr, eb1,
                               c1, (u64*)(h1b + ((s + 1) & 1) * 16384), (u64*)h1f,
                               encb + s * 512, 128 * 512, j0);
            }
        }
        gbar(flags, 64, (unsigned)(t + 1));
    }
}

// ============ decoder step kernels (stream-launched, plain memory ops) ============
// k_dattn: blocks 0-31 attention for row b; 32-63 g0h slab; 64-95 g1h slab.
__global__ __launch_bounds__(256) void k_dattn(
    const __hip_bfloat16* __restrict__ enc_projb, const __hip_bfloat16* __restrict__ enc_outb,
    const int* __restrict__ src_tok, const float* __restrict__ v_w,
    const float* __restrict__ attn_W, const float* __restrict__ attn_b,
    const float* __restrict__ coal_w, const float* __restrict__ coal_b,
    const __hip_bfloat16* __restrict__ dWhh0T, const __hip_bfloat16* __restrict__ dWhh1T,
    const float* __restrict__ h0fc, const float* __restrict__ h1fc,
    const __hip_bfloat16* __restrict__ h0bc, const __hip_bfloat16* __restrict__ h1bc,
    __hip_bfloat16* __restrict__ wctxb, __hip_bfloat16* __restrict__ XoutT,
    float* __restrict__ g0slab, float* __restrict__ g1slab)
{
    __shared__ __align__(16) char shm[32768];
    __shared__ float rinvs;
    __bf16* As0 = (__bf16*)shm;
    int bid = blockIdx.x, tx = threadIdx.x;

    if (bid < 32) {
        int b = bid;
        float* q   = (float*)shm;          // 512
        float* aqs = q + 512;              // 512
        float* vws = aqs + 512;            // 512
        float* ws  = vws + 512;            // 128
        const float* hrow = (b < 16) ? (h0fc + b * 1024) : (h1fc + (b - 16) * 1024);
        float cw0 = coal_w[0], cw1 = coal_w[1], cb = coal_b[0];
        for (int j = tx; j < 512; j += 256) {
            float2 pv = *(const float2*)(hrow + 2 * j);
            q[j] = fmaxf(0.f, pv.x * cw0 + pv.y * cw1 + cb);
        }
        for (int i = tx; i < 512; i += 256) vws[i] = v_w[i];
        __syncthreads();
        // aq[i] = attn_b[i] + sum_j q[j]*Wq[j][i]  — coalesced f32 attn_W
        float a0 = attn_b[tx], a1 = attn_b[tx + 256];
#pragma unroll 8
        for (int j = 0; j < 512; ++j) {
            float qj = q[j];
            a0 += qj * attn_W[(size_t)j * 512 + tx];
            a1 += qj * attn_W[(size_t)j * 512 + tx + 256];
        }
        aqs[tx] = a0; aqs[tx + 256] = a1;
        __syncthreads();
        // scores: 2 lanes per s
        int s = tx >> 1, half = tx & 1;
        const unsigned short* epr = (const unsigned short*)enc_projb
                                    + ((size_t)(b * 128 + s)) * 512 + half * 256;
        float s0 = 0.f, s1 = 0.f, s2 = 0.f, s3 = 0.f;
#pragma unroll 4
        for (int ii = 0; ii < 256; ii += 8) {
            bf16x8 f8 = *(const bf16x8*)(epr + ii);
            int ib = half * 256 + ii;
            s0 += tanh_c((float)f8[0] + aqs[ib])     * vws[ib];
            s1 += tanh_c((float)f8[1] + aqs[ib + 1]) * vws[ib + 1];
            s2 += tanh_c((float)f8[2] + aqs[ib + 2]) * vws[ib + 2];
            s3 += tanh_c((float)f8[3] + aqs[ib + 3]) * vws[ib + 3];
            s0 += tanh_c((float)f8[4] + aqs[ib + 4]) * vws[ib + 4];
            s1 += tanh_c((float)f8[5] + aqs[ib + 5]) * vws[ib + 5];
            s2 += tanh_c((float)f8[6] + aqs[ib + 6]) * vws[ib + 6];
            s3 += tanh_c((float)f8[7] + aqs[ib + 7]) * vws[ib + 7];
        }
        float p = (s0 + s1) + (s2 + s3);
        p += __shfl_xor(p, 1, 64);
        if (half == 0)
            ws[s] = (src_tok[b * 128 + s] != 1) ? __expf(p) : 0.f;
        __syncthreads();
        if (tx < 64) {
            float ss = ws[tx] + ws[tx + 64];
#pragma unroll
            for (int o = 32; o > 0; o >>= 1) ss += __shfl_down(ss, o, 64);
            if (tx == 0) rinvs = 1.0f / ss;
        }
        __syncthreads();
        float rinv = rinvs;
        const unsigned short* eo = (const unsigned short*)enc_outb + (size_t)b * 65536;
        int i0 = tx * 2;
        float c0a = 0.f, c1a = 0.f;
#pragma unroll 4
        for (int s2i = 0; s2i < 128; ++s2i) {
            unsigned pk2 = *(const unsigned*)(eo + (size_t)s2i * 512 + i0);
            float wv = ws[s2i];
            c0a += wv * bf2f((unsigned short)(pk2 & 0xffffu));
            c1a += wv * bf2f((unsigned short)(pk2 >> 16));
        }
        c0a *= rinv; c1a *= rinv;
        unsigned pk = (unsigned)bfbits(c0a) | ((unsigned)bfbits(c1a) << 16);
        *((unsigned*)wctxb + ((b * 512 + i0) >> 1)) = pk;
        *((unsigned*)XoutT + (((size_t)b * KOUT + 512 + i0) >> 1)) = pk;
    } else {
        int tile = (bid < 64) ? bid - 32 : bid - 64;
        const __hip_bfloat16* hsrc = (bid < 64) ? h0bc : h1bc;
        const __hip_bfloat16* WT = (bid < 64) ? dWhh0T : dWhh1T;
        float* slab = ((bid < 64) ? g0slab : g1slab) + tile * 2048;
        int j0 = tile * 16;
        stage_a<false>((const u64*)hsrc, As0);
        __syncthreads();
        int w = tx >> 6, lane = tx & 63;
        int fr = lane & 15, kg = lane >> 4;
        int colB = w * 512 + j0 + fr;
        f32x4 acc[2];
        acc[0] = (f32x4){0.f, 0.f, 0.f, 0.f};
        acc[1] = (f32x4){0.f, 0.f, 0.f, 0.f};
        mfma_pass(As0, (const unsigned short*)WT, colB, kg, fr, acc);
        float* outp = slab + w * 512;
#pragma unroll
        for (int m = 0; m < 2; ++m)
#pragma unroll
            for (int qd = 0; qd < 4; ++qd)
                outp[(m * 16 + kg * 4 + qd) * 16 + fr] = acc[m][qd];
    }
}

__global__ __launch_bounds__(256) void k_dcell0(
    const __hip_bfloat16* __restrict__ wctxb, const __hip_bfloat16* __restrict__ Wih0wT,
    const __hip_bfloat16* __restrict__ xpart, const float* __restrict__ g0slab,
    float* __restrict__ c0d, __hip_bfloat16* __restrict__ hb_nxt, float* __restrict__ hf_nxt)
{
    __shared__ __align__(16) char shm[32768];
    __bf16* As0 = (__bf16*)shm;
    int j0 = blockIdx.x * 16;
    stage_a<false>((const u64*)wctxb, As0);
    __syncthreads();
    mfma_gates(As0, nullptr, Wih0wT, nullptr, j0, (float*)As0);
    cell_epi<false>((float*)As0, g0slab + blockIdx.x * 2048, xpart, nullptr,
                    c0d, (u64*)hb_nxt, (u64*)hf_nxt, nullptr, 0, j0);
}

__global__ __launch_bounds__(256) void k_dcell1(
    const __hip_bfloat16* __restrict__ h0b_nxt, const __hip_bfloat16* __restrict__ Wih1T,
    const float* __restrict__ db1, const float* __restrict__ g1slab,
    float* __restrict__ c1d, __hip_bfloat16* __restrict__ hb_nxt, float* __restrict__ hf_nxt,
    __hip_bfloat16* __restrict__ XoutT)
{
    __shared__ __align__(16) char shm[32768];
    __bf16* As0 = (__bf16*)shm;
    int j0 = blockIdx.x * 16;
    stage_a<false>((const u64*)h0b_nxt, As0);
    __syncthreads();
    mfma_gates(As0, nullptr, Wih1T, nullptr, j0, (float*)As0);
    cell_epi<false>((float*)As0, g1slab + blockIdx.x * 2048, nullptr, db1,
                    c1d, (u64*)hb_nxt, (u64*)hf_nxt, XoutT, KOUT, j0);
}

// ============ generic MFMA GEMM: C(MxN) = A(MxK)bf16 @ BT(NxK)bf16 + bias ============
__global__ __launch_bounds__(256) void k_mfma(
    const __hip_bfloat16* __restrict__ A, const __hip_bfloat16* __restrict__ BT,
    const float* __restrict__ bias, float* __restrict__ Cf,
    __hip_bfloat16* __restrict__ Cb, int M, int N, int K)
{
    __shared__ __bf16 As[128][72];
    __shared__ __bf16 Bs[128][72];
    const unsigned short* Aw = (const unsigned short*)A;
    const unsigned short* Bw = (const unsigned short*)BT;
    int n0 = blockIdx.x * 128, m0 = blockIdx.y * 128;
    int tx = threadIdx.x;
    int w = tx >> 6, lane = tx & 63;
    int wm = (w >> 1) * 64, wn = (w & 1) * 64;
    int fr = lane & 15, kg = lane >> 4;
    f32x4 acc[4][4];
#pragma unroll
    for (int mi = 0; mi < 4; mi++)
#pragma unroll
        for (int ni = 0; ni < 4; ni++) acc[mi][ni] = (f32x4){0.f, 0.f, 0.f, 0.f};

    for (int k0 = 0; k0 < K; k0 += 64) {
        __syncthreads();
#pragma unroll
        for (int p = 0; p < 4; p++) {
            int ch = tx + p * 256;
            int r = ch >> 3, cc = (ch & 7) * 8;
            uint4 va = {0u, 0u, 0u, 0u};
            int m = m0 + r;
            if (m < M) va = *(const uint4*)(Aw + (size_t)m * K + k0 + cc);
            *(uint4*)(&As[r][cc]) = va;
            uint4 vb = *(const uint4*)(Bw + (size_t)(n0 + r) * K + k0 + cc);
            *(uint4*)(&Bs[r][cc]) = vb;
        }
        __syncthreads();
#pragma unroll
        for (int kk = 0; kk < 64; kk += 32) {
            bf16x8 af[4], bfv[4];
#pragma unroll
            for (int i = 0; i < 4; i++) {
                af[i]  = *(const bf16x8*)(&As[wm + i * 16 + fr][kk + kg * 8]);
                bfv[i] = *(const bf16x8*)(&Bs[wn + i * 16 + fr][kk + kg * 8]);
            }
#pragma unroll
            for (int mi = 0; mi < 4; mi++)
#pragma unroll
                for (int ni = 0; ni < 4; ni++)
                    acc[mi][ni] = __builtin_amdgcn_mfma_f32_16x16x32_bf16(
                        af[mi], bfv[ni], acc[mi][ni], 0, 0, 0);
        }
    }
#pragma unroll
    for (int ni = 0; ni < 4; ni++) {
        int n = n0 + wn + ni * 16 + fr;
        float bv = bias ? bias[n] : 0.f;
#pragma unroll
        for (int mi = 0; mi < 4; mi++) {
#pragma unroll
            for (int qd = 0; qd < 4; qd++) {
                int R = m0 + wm + mi * 16 + kg * 4 + qd;
                if (R < M) {
                    float v = acc[mi][ni][qd] + bv;
                    if (Cf) Cf[(size_t)R * N + n] = v;
                    else    Cb[(size_t)R * N + n] = __float2bfloat16(v);
                }
            }
        }
    }
}

// ============ small kernels ============
__global__ __launch_bounds__(256) void k_init_dec(
    const float* __restrict__ h0e, const float* __restrict__ h1e,
    const float* __restrict__ c0e, const float* __restrict__ c1e,
    float* __restrict__ h0fd, float* __restrict__ h1fd,
    __hip_bfloat16* __restrict__ h0bd, __hip_bfloat16* __restrict__ h1bd,
    float* __restrict__ c0d, float* __restrict__ c1d)
{
    int idx = blockIdx.x * 256 + threadIdx.x;
    float a = h0e[idx], b = h1e[idx];
    h0fd[idx] = a; h1fd[idx] = b;
    h0bd[idx] = __float2bfloat16(a);
    h1bd[idx] = __float2bfloat16(b);
    c0d[idx] = c0e[idx];
    c1d[idx] = c1e[idx];
}

__global__ __launch_bounds__(256) void k_bos(float* __restrict__ out)
{
    int b = blockIdx.y;
    int i = blockIdx.x * 256 + threadIdx.x;
    out[(size_t)b * (Tq * Vq) + i] = 2.0f;
}

__global__ __launch_bounds__(256) void k_finalize(
    const float* __restrict__ h0f, const float* __restrict__ h1f,
    const float* __restrict__ c0f, const float* __restrict__ c1f,
    float* __restrict__ out)
{
    int idx = blockIdx.x * 256 + threadIdx.x;
    size_t base = (size_t)Bq * Tq * Vq;
    out[base + idx] = h0f[idx];
    out[base + 16384 + idx] = h1f[idx];
    out[base + 32768 + idx] = c0f[idx];
    out[base + 49152 + idx] = c1f[idx];
}

// ============ logits GEMM (scatter epilogue) ============
__global__ __launch_bounds__(256) void k_logits(
    const __hip_bfloat16* __restrict__ A, const __hip_bfloat16* __restrict__ Bt,
    const float* __restrict__ bias, float* __restrict__ out)
{
    __shared__ __bf16 As[128][72];
    __shared__ __bf16 Bs[128][72];
    const unsigned short* Aw = (const unsigned short*)A;
    const unsigned short* Bw = (const unsigned short*)Bt;
    int n0 = blockIdx.x * 128, m0 = blockIdx.y * 128;
    int tx = threadIdx.x;
    int w = tx >> 6, lane = tx & 63;
    int wm = (w >> 1) * 64, wn = (w & 1) * 64;
    int fr = lane & 15, kg = lane >> 4;
    f32x4 acc[4][4];
#pragma unroll
    for (int mi = 0; mi < 4; mi++)
#pragma unroll
        for (int ni = 0; ni < 4; ni++) acc[mi][ni] = (f32x4){0.f, 0.f, 0.f, 0.f};

    for (int k0 = 0; k0 < 1280; k0 += 64) {
        __syncthreads();
#pragma unroll
        for (int p = 0; p < 4; p++) {
            int ch = tx + p * 256;
            int r = ch >> 3, cc = (ch & 7) * 8;
            uint4 va = {0u, 0u, 0u, 0u};
            int m = m0 + r;
            if (m < 2016) va = *(const uint4*)(Aw + (size_t)m * 1280 + k0 + cc);
            *(uint4*)(&As[r][cc]) = va;
            uint4 vb = *(const uint4*)(Bw + (size_t)(n0 + r) * 1280 + k0 + cc);
            *(uint4*)(&Bs[r][cc]) = vb;
        }
        __syncthreads();
#pragma unroll
        for (int kk = 0; kk < 64; kk += 32) {
            bf16x8 af[4], bfv[4];
#pragma unroll
            for (int i = 0; i < 4; i++) {
                af[i]  = *(const bf16x8*)(&As[wm + i * 16 + fr][kk + kg * 8]);
                bfv[i] = *(const bf16x8*)(&Bs[wn + i * 16 + fr][kk + kg * 8]);
            }
#pragma unroll
            for (int mi = 0; mi < 4; mi++)
#pragma unroll
                for (int ni = 0; ni < 4; ni++)
                    acc[mi][ni] = __builtin_amdgcn_mfma_f32_16x16x32_bf16(
                        af[mi], bfv[ni], acc[mi][ni], 0, 0, 0);
        }
    }
#pragma unroll
    for (int ni = 0; ni < 4; ni++) {
        int n = n0 + wn + ni * 16 + fr;
        float bv = bias[n];
#pragma unroll
        for (int mi = 0; mi < 4; mi++) {
#pragma unroll
            for (int qd = 0; qd < 4; qd++) {
                int R = m0 + wm + mi * 16 + kg * 4 + qd;
                if (R < 2016) {
                    int bb = R & 31, ts = R >> 5;
                    out[(size_t)bb * (Tq * Vq) + (size_t)(ts + 1) * Vq + n] =
                        acc[mi][ni][qd] + bv;
                }
            }
        }
    }
}

// ============ launcher ============
extern "C" void kernel_launch(void* const* d_in, const int* in_sizes, int n_in,
                              void* d_out, int out_size, void* d_ws, size_t ws_size,
                              hipStream_t stream)
{
    (void)in_sizes; (void)n_in; (void)out_size; (void)ws_size;
    const int*   src_tok = (const int*)  d_in[0];
    const int*   tgt_tok = (const int*)  d_in[1];
    const float* src_emb = (const float*)d_in[2];
    const float* tgt_emb = (const float*)d_in[3];
    const float* eWih0   = (const float*)d_in[4];
    const float* eWhh0   = (const float*)d_in[5];
    const float* eb0     = (const float*)d_in[6];
    const float* eWih1   = (const float*)d_in[7];
    const float* eWhh1   = (const float*)d_in[8];
    const float* eb1     = (const float*)d_in[9];
    const float* dWih0   = (const float*)d_in[10];
    const float* dWhh0   = (const float*)d_in[11];
    const float* db0     = (const float*)d_in[12];
    const float* dWih1   = (const float*)d_in[13];
    const float* dWhh1   = (const float*)d_in[14];
    const float* db1     = (const float*)d_in[15];
    const float* attn_W  = (const float*)d_in[16];
    const float* attn_b  = (const float*)d_in[17];
    const float* v_w     = (const float*)d_in[18];
    const float* coal_w  = (const float*)d_in[19];
    const float* coal_b  = (const float*)d_in[20];
    const float* out_W   = (const float*)d_in[21];
    const float* out_b   = (const float*)d_in[22];
    float* out = (float*)d_out;

    char* ws = (char*)d_ws;
    size_t off = 0;
    auto alloc = [&](size_t bytes) -> char* {
        char* p = ws + off;
        off += (bytes + 255) & ~(size_t)255;
        return p;
    };
    typedef __hip_bfloat16 BF;
    BF* X0b     = (BF*)alloc(4096ull * 2048 * 2);
    BF* Xembb   = (BF*)alloc(2016ull * 2048 * 2);
    BF* x_srcb  = (BF*)alloc(4096ull * 256 * 2);
    BF* embtb   = (BF*)alloc(2016ull * 256 * 2);
    BF* ys0b    = (BF*)alloc(128ull * 16384 * 2);
    BF* enc_outb  = (BF*)alloc(4096ull * 512 * 2);
    BF* enc_projb = (BF*)alloc(4096ull * 512 * 2);
    BF* wctxb     = (BF*)alloc(16384ull * 2);
    BF* Xout      = (BF*)alloc(2016ull * 1280 * 2);
    BF* Wt        = (BF*)alloc(32000ull * 1280 * 2);
    BF* eWhh0T  = (BF*)alloc(2048ull * 512 * 2);
    BF* eWih1T  = (BF*)alloc(2048ull * 512 * 2);
    BF* eWhh1T  = (BF*)alloc(2048ull * 512 * 2);
    BF* dWih0wT = (BF*)alloc(2048ull * 512 * 2);
    BF* dWhh0T  = (BF*)alloc(2048ull * 512 * 2);
    BF* dWih1T  = (BF*)alloc(2048ull * 512 * 2);
    BF* dWhh1T  = (BF*)alloc(2048ull * 512 * 2);
    BF* eWih0T  = (BF*)alloc(2048ull * 256 * 2);
    BF* dWih0eT = (BF*)alloc(2048ull * 256 * 2);
    BF* WeT     = (BF*)alloc(512ull * 512 * 2);
    BF* h0b_e   = (BF*)alloc(2ull * 16384 * 2);
    BF* h1b_e   = (BF*)alloc(2ull * 16384 * 2);
    float* h0f_e = (float*)alloc(16384ull * 4);
    float* h1f_e = (float*)alloc(16384ull * 4);
    float* c0e   = (float*)alloc(16384ull * 4);
    float* c1e   = (float*)alloc(16384ull * 4);
    float* h0fd  = (float*)alloc(2ull * 16384 * 4);
    float* h1fd  = (float*)alloc(2ull * 16384 * 4);
    BF* h0bd     = (BF*)alloc(2ull * 16384 * 2);
    BF* h1bd     = (BF*)alloc(2ull * 16384 * 2);
    float* c0d   = (float*)alloc(16384ull * 4);
    float* c1d   = (float*)alloc(16384ull * 4);
    float* g0slab = (float*)alloc(32ull * 2048 * 4);
    float* g1slab = (float*)alloc(32ull * 2048 * 4);
    unsigned* encFlags = (unsigned*)alloc(64 * 32 * 4);   // 64 blocks x 128B

    hipMemsetAsync(encFlags, 0, 64 * 32 * 4, stream);
    hipMemsetAsync(h0b_e, 0, 2 * 16384 * 2, stream);
    hipMemsetAsync(h1b_e, 0, 2 * 16384 * 2, stream);
    hipMemsetAsync(c0e, 0, 16384 * 4, stream);
    hipMemsetAsync(c1e, 0, 16384 * 4, stream);

    // embeddings
    k_embed_src<<<4096, 256, 0, stream>>>(src_tok, src_emb, x_srcb);
    k_embed_tgt<<<2016, 256, 0, stream>>>(tgt_tok, tgt_emb, embtb, Xout);

    // weight transposes (f32 -> bf16, N-major)
    k_transpose_bf16<<<dim3(64, 16), 256, 0, stream>>>(eWhh0, eWhh0T, 512, 2048);
    k_transpose_bf16<<<dim3(64, 16), 256, 0, stream>>>(eWih1, eWih1T, 512, 2048);
    k_transpose_bf16<<<dim3(64, 16), 256, 0, stream>>>(eWhh1, eWhh1T, 512, 2048);
    k_transpose_bf16<<<dim3(64, 16), 256, 0, stream>>>(dWih0 + 256 * 2048, dWih0wT, 512, 2048);
    k_transpose_bf16<<<dim3(64, 16), 256, 0, stream>>>(dWhh0, dWhh0T, 512, 2048);
    k_transpose_bf16<<<dim3(64, 16), 256, 0, stream>>>(dWih1, dWih1T, 512, 2048);
    k_transpose_bf16<<<dim3(64, 16), 256, 0, stream>>>(dWhh1, dWhh1T, 512, 2048);
    k_transpose_bf16<<<dim3(64, 8), 256, 0, stream>>>(eWih0, eWih0T, 256, 2048);
    k_transpose_bf16<<<dim3(64, 8), 256, 0, stream>>>(dWih0, dWih0eT, 256, 2048);
    k_transpose_bf16<<<dim3(16, 16), 256, 0, stream>>>(attn_W + 512 * 512, WeT, 512, 512);
    k_transpose_bf16<<<dim3(1000, 40), 256, 0, stream>>>(out_W, Wt, 1280, 32000);

    // input-side GEMMs (bf16 out)
    k_mfma<<<dim3(16, 32), 256, 0, stream>>>(x_srcb, eWih0T, eb0, nullptr, X0b, 4096, 2048, 256);
    k_mfma<<<dim3(16, 16), 256, 0, stream>>>(embtb, dWih0eT, db0, nullptr, Xembb, 2016, 2048, 256);
    k_bos<<<dim3(125, 32), 256, 0, stream>>>(out);

    // persistent encoder
    k_enc_persist<<<64, 256, 0, stream>>>(X0b, eWhh0T, eWih1T, eWhh1T, eb1,
                                          h0b_e, h1b_e, h0f_e, h1f_e, c0e, c1e,
                                          ys0b, enc_outb, encFlags);

    // enc_proj = enc_out @ We (bf16 out)
    k_mfma<<<dim3(4, 32), 256, 0, stream>>>(enc_outb, WeT, nullptr, nullptr, enc_projb, 4096, 512, 512);

    k_init_dec<<<64, 256, 0, stream>>>(h0f_e, h1f_e, c0e, c1e,
                                       h0fd, h1fd, h0bd, h1bd, c0d, c1d);

    // decoder: 3 stream launches per step
    for (int t = 0; t < TD; ++t) {
        int cur = t & 1, nxt = cur ^ 1;
        BF* XoutT = Xout + (size_t)t * 32 * KOUT;
        k_dattn<<<96, 256, 0, stream>>>(enc_projb, enc_outb, src_tok, v_w,
                                        attn_W, attn_b, coal_w, coal_b,
                                        dWhh0T, dWhh1T,
                                        h0fd + cur * 16384, h1fd + cur * 16384,
                                        h0bd + cur * 16384, h1bd + cur * 16384,
                                        wctxb, XoutT, g0slab, g1slab);
        k_dcell0<<<32, 256, 0, stream>>>(wctxb, dWih0wT,
                                         Xembb + (size_t)t * 32 * 2048, g0slab,
                                         c0d, h0bd + nxt * 16384, h0fd + nxt * 16384);
        k_dcell1<<<32, 256, 0, stream>>>(h0bd + nxt * 16384, dWih1T, db1, g1slab,
                                         c1d, h1bd + nxt * 16384, h1fd + nxt * 16384,
                                         XoutT);
    }

    k_finalize<<<64, 256, 0, stream>>>(h0fd + (TD & 1) * 16384, h1fd + (TD & 1) * 16384,
                                       c0d, c1d, out);
    k_logits<<<dim3(250, 16), 256, 0, stream>>>(Xout, Wt, out_b, out);
}

// Round 10
// 5297.441 us; speedup vs baseline: 1.0925x; 1.0345x over previous
//
#include <hip/hip_runtime.h>
#include <hip/hip_bf16.h>

typedef __bf16 bf16x8 __attribute__((ext_vector_type(8)));
typedef float f32x4 __attribute__((ext_vector_type(4)));
typedef unsigned long long u64;

#define DEV static __device__ __forceinline__

constexpr int Bq = 32, Sq = 128, Tq = 64, Eq = 256, Hq = 512, Vq = 32000;
constexpr int TD = 63;            // decode steps (T-1)
constexpr int KOUT = 1280;        // 2H + E
constexpr float SQRTE = 16.0f;    // sqrt(256)

DEV float sigf(float x) { return 1.0f / (1.0f + __expf(-x)); }
DEV float tanh_fast(float x) {
    float ax = fabsf(x);
    float t = __expf(-2.f * ax);
    float r = (1.f - t) / (1.f + t);
    return x < 0.f ? -r : r;
}
DEV float tanh_c(float x) {
    float xc = fminf(fmaxf(x, -15.f), 15.f);
    float t = __expf(2.f * xc);
    return (t - 1.f) / (t + 1.f);
}

// ---- agent-scope access helpers (encoder persistent kernel only) ----
DEV u64 ldc(const u64* p) {
    return __hip_atomic_load(p, __ATOMIC_RELAXED, __HIP_MEMORY_SCOPE_AGENT);
}
DEV unsigned ldc32(const unsigned* p) {
    return __hip_atomic_load(p, __ATOMIC_RELAXED, __HIP_MEMORY_SCOPE_AGENT);
}
DEV void stc(u64* p, u64 v) {
    __hip_atomic_store(p, v, __ATOMIC_RELAXED, __HIP_MEMORY_SCOPE_AGENT);
}
DEV void stc32(unsigned* p, unsigned v) {
    __hip_atomic_store(p, v, __ATOMIC_RELAXED, __HIP_MEMORY_SCOPE_AGENT);
}
DEV unsigned short bfbits(float f) {
    __bf16 h = (__bf16)f;
    return __builtin_bit_cast(unsigned short, h);
}
DEV float bf2f(unsigned short u) {
    __bf16 h = __builtin_bit_cast(__bf16, u);
    return (float)h;
}
DEV u64 pack4bf(float a, float b, float c, float d) {
    return (u64)bfbits(a) | ((u64)bfbits(b) << 16) |
           ((u64)bfbits(c) << 32) | ((u64)bfbits(d) << 48);
}
DEV u64 pack2f(float a, float b) {
    return (u64)__float_as_uint(a) | ((u64)__float_as_uint(b) << 32);
}
template<bool C> DEV u64 ld64g(const u64* p) { return C ? ldc(p) : *p; }
template<bool C> DEV void st64g(u64* p, u64 v) { if (C) stc(p, v); else *p = v; }
DEV void drain_vm() { asm volatile("s_waitcnt vmcnt(0)" ::: "memory"); }

// ---- encoder wait: lanes 0-31 check layer0 flags >= need0, 32-63 layer1 >= need1
DEV void encwait(unsigned* flags, unsigned need0, unsigned need1) {
    __syncthreads();
    if (threadIdx.x < 64) {
        int lane = threadIdx.x;
        unsigned need = (lane < 32) ? need0 : need1;
        for (;;) {
            unsigned v = ldc32(flags + lane * 32);
            if (__all((int)(v >= need))) break;
            __builtin_amdgcn_s_sleep(1);
        }
    }
    __syncthreads();
}

// ============ embeddings (bf16 out) ============
__global__ __launch_bounds__(256) void k_embed_src(const int* __restrict__ tok,
                                                   const float* __restrict__ emb,
                                                   __hip_bfloat16* __restrict__ x)
{
    int idx = blockIdx.x * 256 + threadIdx.x;
    int e = idx & (Eq - 1);
    int r = idx >> 8;
    int b = r & 31, t = r >> 5;
    x[idx] = __float2bfloat16(emb[(size_t)tok[b * Sq + t] * Eq + e] * SQRTE);
}

__global__ __launch_bounds__(256) void k_embed_tgt(const int* __restrict__ tok,
                                                   const float* __restrict__ emb,
                                                   __hip_bfloat16* __restrict__ embt,
                                                   __hip_bfloat16* __restrict__ Xout)
{
    int idx = blockIdx.x * 256 + threadIdx.x;
    int e = idx & (Eq - 1);
    int r = idx >> 8;
    int b = r & 31, t = r >> 5;
    float v = fmaxf(0.f, emb[(size_t)tok[b * Tq + t] * Eq + e] * SQRTE);
    embt[idx] = __float2bfloat16(v);
    Xout[(size_t)r * KOUT + 1024 + e] = __float2bfloat16(v);
}

// ============ transpose + cast W (K x N) -> Wt (N x K) bf16 ============
__global__ __launch_bounds__(256) void k_transpose_bf16(const float* __restrict__ W,
                                                        __hip_bfloat16* __restrict__ Wt,
                                                        int K, int N)
{
    __shared__ float tile[32][33];
    int nb = blockIdx.x * 32, kb = blockIdx.y * 32;
    int c = threadIdx.x & 31, r4 = threadIdx.x >> 5;
    for (int i = 0; i < 32; i += 8)
        tile[r4 + i][c] = W[(size_t)(kb + r4 + i) * N + nb + c];
    __syncthreads();
    for (int i = 0; i < 32; i += 8) {
        int rr = r4 + i;
        Wt[(size_t)(nb + rr) * K + kb + c] = __float2bfloat16(tile[c][rr]);
    }
}

// fused multi-matrix transpose (10 small weights in one launch)
struct TD10 {
    const float* s[10];
    __hip_bfloat16* d[10];
    int K[10];
    int N[10];
};
__global__ __launch_bounds__(256) void k_transpose_multi(TD10 td)
{
    __shared__ float tile[32][33];
    int m = blockIdx.y;
    int K = td.K[m], N = td.N[m];
    int ntn = N >> 5;
    int nb = (blockIdx.x % ntn) * 32;
    int kb = (blockIdx.x / ntn) * 32;
    if (kb >= K) return;
    const float* W = td.s[m];
    __hip_bfloat16* Wt = td.d[m];
    int c = threadIdx.x & 31, r4 = threadIdx.x >> 5;
    for (int i = 0; i < 32; i += 8)
        tile[r4 + i][c] = W[(size_t)(kb + r4 + i) * N + nb + c];
    __syncthreads();
    for (int i = 0; i < 32; i += 8) {
        int rr = r4 + i;
        Wt[(size_t)(nb + rr) * K + kb + c] = __float2bfloat16(tile[c][rr]);
    }
}

// ============ MFMA recurrent helpers (K=512, A=32x512 in LDS, swizzled) ============
template<bool C>
DEV void stage_a(const u64* src, __bf16* As) {
    int tx = threadIdx.x;
#pragma unroll
    for (int p = 0; p < 8; ++p) {
        int c = tx + p * 256;
        int row = c >> 6, kc = c & 63;
        u64 v0 = ld64g<C>(src + c * 2);
        u64 v1 = ld64g<C>(src + c * 2 + 1);
        int kd = kc ^ (row & 7);
        *(u64*)(As + row * 512 + kd * 8) = v0;
        *(u64*)(As + row * 512 + kd * 8 + 4) = v1;
    }
}

DEV void mfma_pass(const __bf16* As, const unsigned short* BT, int colB,
                   int kg, int fr, f32x4* acc) {
    const unsigned short* bp = BT + (size_t)colB * 512 + kg * 8;
    int f7 = fr & 7;
#pragma unroll
    for (int k0 = 0; k0 < 512; k0 += 32) {
        int cidx = ((k0 >> 3) | kg) ^ f7;
        bf16x8 bfv = *(const bf16x8*)(bp + k0);
        bf16x8 af0 = *(const bf16x8*)(As + fr * 512 + cidx * 8);
        bf16x8 af1 = *(const bf16x8*)(As + (16 + fr) * 512 + cidx * 8);
        acc[0] = __builtin_amdgcn_mfma_f32_16x16x32_bf16(af0, bfv, acc[0], 0, 0, 0);
        acc[1] = __builtin_amdgcn_mfma_f32_16x16x32_bf16(af1, bfv, acc[1], 0, 0, 0);
    }
}

DEV void mfma_gates(const __bf16* As0, const __bf16* As1,
                    const __hip_bfloat16* B0T, const __hip_bfloat16* B1T,
                    int j0, float* gbuf)
{
    int tx = threadIdx.x, w = tx >> 6, lane = tx & 63;
    int fr = lane & 15, kg = lane >> 4;
    int colB = w * 512 + j0 + fr;
    f32x4 acc[2];
    acc[0] = (f32x4){0.f, 0.f, 0.f, 0.f};
    acc[1] = (f32x4){0.f, 0.f, 0.f, 0.f};
    mfma_pass(As0, (const unsigned short*)B0T, colB, kg, fr, acc);
    if (B1T) mfma_pass(As1, (const unsigned short*)B1T, colB, kg, fr, acc);
    __syncthreads();
    float* gw = gbuf + w * 512;
#pragma unroll
    for (int m = 0; m < 2; ++m)
#pragma unroll
        for (int qd = 0; qd < 4; ++qd)
            gw[(m * 16 + kg * 4 + qd) * 16 + fr] = acc[m][qd];
    __syncthreads();
}

template<bool C>
DEV void cell_epi(const float* gbuf,
                  const __hip_bfloat16* xpart, const float* bias,
                  float* cbuf, u64* hb, u64* hf,
                  __hip_bfloat16* eb, int ebs, int j0)
{
    int tx = threadIdx.x;
    if (tx >= 128) return;
    int b = tx >> 2, jg = tx & 3;
    int jj0 = jg * 4;
    int j = j0 + jj0;
    float g[4][4];
#pragma unroll
    for (int gi = 0; gi < 4; ++gi) {
        int idx = gi * 512 + b * 16 + jj0;
        float4 gv = *(const float4*)(gbuf + idx);
        g[gi][0] = gv.x; g[gi][1] = gv.y; g[gi][2] = gv.z; g[gi][3] = gv.w;
        if (xpart) {
            u64 xv = *(const u64*)((const unsigned short*)xpart + b * 2048 + gi * 512 + j);
#pragma unroll
            for (int e = 0; e < 4; ++e)
                g[gi][e] += bf2f((unsigned short)(xv >> (16 * e)));
        }
        if (bias) {
            float4 bv = *(const float4*)(bias + gi * 512 + j);
            g[gi][0] += bv.x; g[gi][1] += bv.y; g[gi][2] += bv.z; g[gi][3] += bv.w;
        }
    }
    float4 cv = *(float4*)(cbuf + b * 512 + j);
    float cc[4] = {cv.x, cv.y, cv.z, cv.w};
    float hv[4];
#pragma unroll
    for (int e = 0; e < 4; ++e) {
        float cn = sigf(g[1][e]) * cc[e] + sigf(g[0][e]) * tanh_fast(g[2][e]);
        cc[e] = cn;
        hv[e] = sigf(g[3][e]) * tanh_fast(cn);
    }
    *(float4*)(cbuf + b * 512 + j) = make_float4(cc[0], cc[1], cc[2], cc[3]);
    u64 hpk = pack4bf(hv[0], hv[1], hv[2], hv[3]);
    st64g<C>(hb + ((b * 512 + j) >> 2), hpk);
    st64g<C>(hf + ((b * 512 + j) >> 1), pack2f(hv[0], hv[1]));
    st64g<C>(hf + ((b * 512 + j) >> 1) + 1, pack2f(hv[2], hv[3]));
    if (eb) st64g<C>((u64*)(eb + (size_t)b * ebs + j), hpk);
}

// ============ persistent encoder: DECOUPLED layer pipelines ============
// blocks 0-31: layer0 free-runs (own 32-flag barrier). blocks 32-63: layer1,
// waits on layer0 flags >= s+1 (ys0[s] ready) and own flags >= s.
__global__ __launch_bounds__(256) void k_enc_persist(
    const __hip_bfloat16* __restrict__ X0b,
    const __hip_bfloat16* __restrict__ eWhh0T, const __hip_bfloat16* __restrict__ eWih1T,
    const __hip_bfloat16* __restrict__ eWhh1T, const float* __restrict__ eb1,
    __hip_bfloat16* __restrict__ h0b, __hip_bfloat16* __restrict__ h1b,
    float* __restrict__ h0f, float* __restrict__ h1f,
    float* __restrict__ c0, float* __restrict__ c1,
    __hip_bfloat16* __restrict__ ys0b,
    __hip_bfloat16* __restrict__ encb,
    unsigned* __restrict__ flags)
{
    __shared__ __align__(16) char shm[65536];
    __bf16* As0 = (__bf16*)shm;
    __bf16* As1 = (__bf16*)(shm + 32768);
    bool lay1 = blockIdx.x >= 32;
    int j0 = (blockIdx.x & 31) * 16;

    if (!lay1) {
        for (int t = 0; t < 128; ++t) {
            encwait(flags, (unsigned)t, 0u);        // own recurrence only
            stage_a<true>((const u64*)(h0b + (t & 1) * 16384), As0);
            __syncthreads();
            mfma_gates(As0, nullptr, eWhh0T, nullptr, j0, (float*)As0);
            cell_epi<true>((float*)As0, X0b + (size_t)t * 32 * 2048, nullptr,
                           c0, (u64*)(h0b + ((t + 1) & 1) * 16384), (u64*)h0f,
                           ys0b + (size_t)t * 16384, 512, j0);
            __syncthreads();
            if (threadIdx.x == 0) {
                drain_vm();
                stc32(flags + blockIdx.x * 32, (unsigned)(t + 1));
            }
        }
    } else {
        for (int s = 0; s < 128; ++s) {
            encwait(flags, (unsigned)(s + 1), (unsigned)s);   // ys0[s] ready + own
            stage_a<true>((const u64*)(ys0b + (size_t)s * 16384), As0);
            stage_a<true>((const u64*)(h1b + (s & 1) * 16384), As1);
            __syncthreads();
            mfma_gates(As0, As1, eWih1T, eWhh1T, j0, (float*)As0);
            cell_epi<true>((float*)As0, nullptr, eb1,
                           c1, (u64*)(h1b + ((s + 1) & 1) * 16384), (u64*)h1f,
                           encb + s * 512, 128 * 512, j0);
            __syncthreads();
            if (threadIdx.x == 0) {
                drain_vm();
                stc32(flags + blockIdx.x * 32, (unsigned)(s + 1));
            }
        }
    }
}

// ============ decoder step kernels (stream-launched, plain memory) ============
// attention only, 32 blocks (one per batch row)
__global__ __launch_bounds__(256) void k_dattn2(
    const __hip_bfloat16* __restrict__ enc_projb, const __hip_bfloat16* __restrict__ enc_outb,
    const int* __restrict__ src_tok, const float* __restrict__ v_w,
    const float* __restrict__ attn_W, const float* __restrict__ attn_b,
    const float* __restrict__ coal_w, const float* __restrict__ coal_b,
    const float* __restrict__ h0fc, const float* __restrict__ h1fc,
    __hip_bfloat16* __restrict__ wctxb, __hip_bfloat16* __restrict__ XoutT)
{
    __shared__ float q[512];
    __shared__ float aqs[512];
    __shared__ float vws[512];
    __shared__ float ws[128];
    __shared__ float rinvs;
    int b = blockIdx.x, tx = threadIdx.x;

    const float* hrow = (b < 16) ? (h0fc + b * 1024) : (h1fc + (b - 16) * 1024);
    float cw0 = coal_w[0], cw1 = coal_w[1], cb = coal_b[0];
    for (int j = tx; j < 512; j += 256) {
        float2 pv = *(const float2*)(hrow + 2 * j);
        q[j] = fmaxf(0.f, pv.x * cw0 + pv.y * cw1 + cb);
    }
    for (int i = tx; i < 512; i += 256) vws[i] = v_w[i];
    __syncthreads();
    // aq[i] = attn_b[i] + sum_j q[j]*Wq[j][i]  — coalesced f32 attn_W
    float a0 = attn_b[tx], a1 = attn_b[tx + 256];
#pragma unroll 8
    for (int j = 0; j < 512; ++j) {
        float qj = q[j];
        a0 += qj * attn_W[(size_t)j * 512 + tx];
        a1 += qj * attn_W[(size_t)j * 512 + tx + 256];
    }
    aqs[tx] = a0; aqs[tx + 256] = a1;
    __syncthreads();
    // scores: 2 lanes per s
    int s = tx >> 1, half = tx & 1;
    const unsigned short* epr = (const unsigned short*)enc_projb
                                + ((size_t)(b * 128 + s)) * 512 + half * 256;
    float s0 = 0.f, s1 = 0.f, s2 = 0.f, s3 = 0.f;
#pragma unroll 4
    for (int ii = 0; ii < 256; ii += 8) {
        bf16x8 f8 = *(const bf16x8*)(epr + ii);
        int ib = half * 256 + ii;
        s0 += tanh_c((float)f8[0] + aqs[ib])     * vws[ib];
        s1 += tanh_c((float)f8[1] + aqs[ib + 1]) * vws[ib + 1];
        s2 += tanh_c((float)f8[2] + aqs[ib + 2]) * vws[ib + 2];
        s3 += tanh_c((float)f8[3] + aqs[ib + 3]) * vws[ib + 3];
        s0 += tanh_c((float)f8[4] + aqs[ib + 4]) * vws[ib + 4];
        s1 += tanh_c((float)f8[5] + aqs[ib + 5]) * vws[ib + 5];
        s2 += tanh_c((float)f8[6] + aqs[ib + 6]) * vws[ib + 6];
        s3 += tanh_c((float)f8[7] + aqs[ib + 7]) * vws[ib + 7];
    }
    float p = (s0 + s1) + (s2 + s3);
    p += __shfl_xor(p, 1, 64);
    if (half == 0)
        ws[s] = (src_tok[b * 128 + s] != 1) ? __expf(p) : 0.f;
    __syncthreads();
    if (tx < 64) {
        float ss = ws[tx] + ws[tx + 64];
#pragma unroll
        for (int o = 32; o > 0; o >>= 1) ss += __shfl_down(ss, o, 64);
        if (tx == 0) rinvs = 1.0f / ss;
    }
    __syncthreads();
    float rinv = rinvs;
    const unsigned short* eo = (const unsigned short*)enc_outb + (size_t)b * 65536;
    int i0 = tx * 2;
    float c0a = 0.f, c1a = 0.f;
#pragma unroll 4
    for (int s2i = 0; s2i < 128; ++s2i) {
        unsigned pk2 = *(const unsigned*)(eo + (size_t)s2i * 512 + i0);
        float wv = ws[s2i];
        c0a += wv * bf2f((unsigned short)(pk2 & 0xffffu));
        c1a += wv * bf2f((unsigned short)(pk2 >> 16));
    }
    c0a *= rinv; c1a *= rinv;
    unsigned pk = (unsigned)bfbits(c0a) | ((unsigned)bfbits(c1a) << 16);
    *((unsigned*)wctxb + ((b * 512 + i0) >> 1)) = pk;
    *((unsigned*)XoutT + (((size_t)b * KOUT + 512 + i0) >> 1)) = pk;
}

// dual-pass LSTM cell (R2-validated shape), 32 blocks
__global__ __launch_bounds__(256) void k_rec(
    const __hip_bfloat16* __restrict__ A0, const __hip_bfloat16* __restrict__ B0T,
    const __hip_bfloat16* __restrict__ A1, const __hip_bfloat16* __restrict__ B1T,
    const __hip_bfloat16* __restrict__ xpart, const float* __restrict__ bias,
    float* __restrict__ cbuf, float* __restrict__ hf, __hip_bfloat16* __restrict__ hb,
    __hip_bfloat16* __restrict__ ebf16, int ebs)
{
    __shared__ __align__(16) char shm[65536];
    __bf16* As0 = (__bf16*)shm;
    __bf16* As1 = (__bf16*)(shm + 32768);
    int j0 = blockIdx.x * 16;
    stage_a<false>((const u64*)A0, As0);
    stage_a<false>((const u64*)A1, As1);
    __syncthreads();
    mfma_gates(As0, As1, B0T, B1T, j0, (float*)As0);
    cell_epi<false>((float*)As0, xpart, bias, cbuf, (u64*)hb, (u64*)hf, ebf16, ebs, j0);
}

// ============ generic MFMA GEMM: C(MxN) = A(MxK)bf16 @ BT(NxK)bf16 + bias ============
__global__ __launch_bounds__(256) void k_mfma(
    const __hip_bfloat16* __restrict__ A, const __hip_bfloat16* __restrict__ BT,
    const float* __restrict__ bias, float* __restrict__ Cf,
    __hip_bfloat16* __restrict__ Cb, int M, int N, int K)
{
    __shared__ __bf16 As[128][72];
    __shared__ __bf16 Bs[128][72];
    const unsigned short* Aw = (const unsigned short*)A;
    const unsigned short* Bw = (const unsigned short*)BT;
    int n0 = blockIdx.x * 128, m0 = blockIdx.y * 128;
    int tx = threadIdx.x;
    int w = tx >> 6, lane = tx & 63;
    int wm = (w >> 1) * 64, wn = (w & 1) * 64;
    int fr = lane & 15, kg = lane >> 4;
    f32x4 acc[4][4];
#pragma unroll
    for (int mi = 0; mi < 4; mi++)
#pragma unroll
        for (int ni = 0; ni < 4; ni++) acc[mi][ni] = (f32x4){0.f, 0.f, 0.f, 0.f};

    for (int k0 = 0; k0 < K; k0 += 64) {
        __syncthreads();
#pragma unroll
        for (int p = 0; p < 4; p++) {
            int ch = tx + p * 256;
            int r = ch >> 3, cc = (ch & 7) * 8;
            uint4 va = {0u, 0u, 0u, 0u};
            int m = m0 + r;
            if (m < M) va = *(const uint4*)(Aw + (size_t)m * K + k0 + cc);
            *(uint4*)(&As[r][cc]) = va;
            uint4 vb = *(const uint4*)(Bw + (size_t)(n0 + r) * K + k0 + cc);
            *(uint4*)(&Bs[r][cc]) = vb;
        }
        __syncthreads();
#pragma unroll
        for (int kk = 0; kk < 64; kk += 32) {
            bf16x8 af[4], bfv[4];
#pragma unroll
            for (int i = 0; i < 4; i++) {
                af[i]  = *(const bf16x8*)(&As[wm + i * 16 + fr][kk + kg * 8]);
                bfv[i] = *(const bf16x8*)(&Bs[wn + i * 16 + fr][kk + kg * 8]);
            }
#pragma unroll
            for (int mi = 0; mi < 4; mi++)
#pragma unroll
                for (int ni = 0; ni < 4; ni++)
                    acc[mi][ni] = __builtin_amdgcn_mfma_f32_16x16x32_bf16(
                        af[mi], bfv[ni], acc[mi][ni], 0, 0, 0);
        }
    }
#pragma unroll
    for (int ni = 0; ni < 4; ni++) {
        int n = n0 + wn + ni * 16 + fr;
        float bv = bias ? bias[n] : 0.f;
#pragma unroll
        for (int mi = 0; mi < 4; mi++) {
#pragma unroll
            for (int qd = 0; qd < 4; qd++) {
                int R = m0 + wm + mi * 16 + kg * 4 + qd;
                if (R < M) {
                    float v = acc[mi][ni][qd] + bv;
                    if (Cf) Cf[(size_t)R * N + n] = v;
                    else    Cb[(size_t)R * N + n] = __float2bfloat16(v);
                }
            }
        }
    }
}

// ============ small kernels ============
__global__ __launch_bounds__(256) void k_init_dec(
    const float* __restrict__ h0e, const float* __restrict__ h1e,
    const float* __restrict__ c0e, const float* __restrict__ c1e,
    float* __restrict__ h0fd, float* __restrict__ h1fd,
    __hip_bfloat16* __restrict__ h0bd, __hip_bfloat16* __restrict__ h1bd,
    float* __restrict__ c0d, float* __restrict__ c1d)
{
    int idx = blockIdx.x * 256 + threadIdx.x;
    float a = h0e[idx], b = h1e[idx];
    h0fd[idx] = a; h1fd[idx] = b;
    h0bd[idx] = __float2bfloat16(a);
    h1bd[idx] = __float2bfloat16(b);
    c0d[idx] = c0e[idx];
    c1d[idx] = c1e[idx];
}

__global__ __launch_bounds__(256) void k_bos(float* __restrict__ out)
{
    int b = blockIdx.y;
    int i = blockIdx.x * 256 + threadIdx.x;
    out[(size_t)b * (Tq * Vq) + i] = 2.0f;
}

__global__ __launch_bounds__(256) void k_finalize(
    const float* __restrict__ h0f, const float* __restrict__ h1f,
    const float* __restrict__ c0f, const float* __restrict__ c1f,
    float* __restrict__ out)
{
    int idx = blockIdx.x * 256 + threadIdx.x;
    size_t base = (size_t)Bq * Tq * Vq;
    out[base + idx] = h0f[idx];
    out[base + 16384 + idx] = h1f[idx];
    out[base + 32768 + idx] = c0f[idx];
    out[base + 49152 + idx] = c1f[idx];
}

// ============ logits GEMM (scatter epilogue) ============
__global__ __launch_bounds__(256) void k_logits(
    const __hip_bfloat16* __restrict__ A, const __hip_bfloat16* __restrict__ Bt,
    const float* __restrict__ bias, float* __restrict__ out)
{
    __shared__ __bf16 As[128][72];
    __shared__ __bf16 Bs[128][72];
    const unsigned short* Aw = (const unsigned short*)A;
    const unsigned short* Bw = (const unsigned short*)Bt;
    int n0 = blockIdx.x * 128, m0 = blockIdx.y * 128;
    int tx = threadIdx.x;
    int w = tx >> 6, lane = tx & 63;
    int wm = (w >> 1) * 64, wn = (w & 1) * 64;
    int fr = lane & 15, kg = lane >> 4;
    f32x4 acc[4][4];
#pragma unroll
    for (int mi = 0; mi < 4; mi++)
#pragma unroll
        for (int ni = 0; ni < 4; ni++) acc[mi][ni] = (f32x4){0.f, 0.f, 0.f, 0.f};

    for (int k0 = 0; k0 < 1280; k0 += 64) {
        __syncthreads();
#pragma unroll
        for (int p = 0; p < 4; p++) {
            int ch = tx + p * 256;
            int r = ch >> 3, cc = (ch & 7) * 8;
            uint4 va = {0u, 0u, 0u, 0u};
            int m = m0 + r;
            if (m < 2016) va = *(const uint4*)(Aw + (size_t)m * 1280 + k0 + cc);
            *(uint4*)(&As[r][cc]) = va;
            uint4 vb = *(const uint4*)(Bw + (size_t)(n0 + r) * 1280 + k0 + cc);
            *(uint4*)(&Bs[r][cc]) = vb;
        }
        __syncthreads();
#pragma unroll
        for (int kk = 0; kk < 64; kk += 32) {
            bf16x8 af[4], bfv[4];
#pragma unroll
            for (int i = 0; i < 4; i++) {
                af[i]  = *(const bf16x8*)(&As[wm + i * 16 + fr][kk + kg * 8]);
                bfv[i] = *(const bf16x8*)(&Bs[wn + i * 16 + fr][kk + kg * 8]);
            }
#pragma unroll
            for (int mi = 0; mi < 4; mi++)
#pragma unroll
                for (int ni = 0; ni < 4; ni++)
                    acc[mi][ni] = __builtin_amdgcn_mfma_f32_16x16x32_bf16(
                        af[mi], bfv[ni], acc[mi][ni], 0, 0, 0);
        }
    }
#pragma unroll
    for (int ni = 0; ni < 4; ni++) {
        int n = n0 + wn + ni * 16 + fr;
        float bv = bias[n];
#pragma unroll
        for (int mi = 0; mi < 4; mi++) {
#pragma unroll
            for (int qd = 0; qd < 4; qd++) {
                int R = m0 + wm + mi * 16 + kg * 4 + qd;
                if (R < 2016) {
                    int bb = R & 31, ts = R >> 5;
                    out[(size_t)bb * (Tq * Vq) + (size_t)(ts + 1) * Vq + n] =
                        acc[mi][ni][qd] + bv;
                }
            }
        }
    }
}

// ============ launcher ============
extern "C" void kernel_launch(void* const* d_in, const int* in_sizes, int n_in,
                              void* d_out, int out_size, void* d_ws, size_t ws_size,
                              hipStream_t stream)
{
    (void)in_sizes; (void)n_in; (void)out_size; (void)ws_size;
    const int*   src_tok = (const int*)  d_in[0];
    const int*   tgt_tok = (const int*)  d_in[1];
    const float* src_emb = (const float*)d_in[2];
    const float* tgt_emb = (const float*)d_in[3];
    const float* eWih0   = (const float*)d_in[4];
    const float* eWhh0   = (const float*)d_in[5];
    const float* eb0     = (const float*)d_in[6];
    const float* eWih1   = (const float*)d_in[7];
    const float* eWhh1   = (const float*)d_in[8];
    const float* eb1     = (const float*)d_in[9];
    const float* dWih0   = (const float*)d_in[10];
    const float* dWhh0   = (const float*)d_in[11];
    const float* db0     = (const float*)d_in[12];
    const float* dWih1   = (const float*)d_in[13];
    const float* dWhh1   = (const float*)d_in[14];
    const float* db1     = (const float*)d_in[15];
    const float* attn_W  = (const float*)d_in[16];
    const float* attn_b  = (const float*)d_in[17];
    const float* v_w     = (const float*)d_in[18];
    const float* coal_w  = (const float*)d_in[19];
    const float* coal_b  = (const float*)d_in[20];
    const float* out_W   = (const float*)d_in[21];
    const float* out_b   = (const float*)d_in[22];
    float* out = (float*)d_out;

    char* ws = (char*)d_ws;
    size_t off = 0;
    auto alloc = [&](size_t bytes) -> char* {
        char* p = ws + off;
        off += (bytes + 255) & ~(size_t)255;
        return p;
    };
    typedef __hip_bfloat16 BF;
    BF* X0b     = (BF*)alloc(4096ull * 2048 * 2);
    BF* Xembb   = (BF*)alloc(2016ull * 2048 * 2);
    BF* x_srcb  = (BF*)alloc(4096ull * 256 * 2);
    BF* embtb   = (BF*)alloc(2016ull * 256 * 2);
    BF* ys0b    = (BF*)alloc(128ull * 16384 * 2);
    BF* enc_outb  = (BF*)alloc(4096ull * 512 * 2);
    BF* enc_projb = (BF*)alloc(4096ull * 512 * 2);
    BF* wctxb     = (BF*)alloc(16384ull * 2);
    BF* Xout      = (BF*)alloc(2016ull * 1280 * 2);
    BF* Wt        = (BF*)alloc(32000ull * 1280 * 2);
    BF* eWhh0T  = (BF*)alloc(2048ull * 512 * 2);
    BF* eWih1T  = (BF*)alloc(2048ull * 512 * 2);
    BF* eWhh1T  = (BF*)alloc(2048ull * 512 * 2);
    BF* dWih0wT = (BF*)alloc(2048ull * 512 * 2);
    BF* dWhh0T  = (BF*)alloc(2048ull * 512 * 2);
    BF* dWih1T  = (BF*)alloc(2048ull * 512 * 2);
    BF* dWhh1T  = (BF*)alloc(2048ull * 512 * 2);
    BF* eWih0T  = (BF*)alloc(2048ull * 256 * 2);
    BF* dWih0eT = (BF*)alloc(2048ull * 256 * 2);
    BF* WeT     = (BF*)alloc(512ull * 512 * 2);
    BF* h0b_e   = (BF*)alloc(2ull * 16384 * 2);
    BF* h1b_e   = (BF*)alloc(2ull * 16384 * 2);
    float* h0f_e = (float*)alloc(16384ull * 4);
    float* h1f_e = (float*)alloc(16384ull * 4);
    float* c0e   = (float*)alloc(16384ull * 4);
    float* c1e   = (float*)alloc(16384ull * 4);
    float* h0fd  = (float*)alloc(2ull * 16384 * 4);
    float* h1fd  = (float*)alloc(2ull * 16384 * 4);
    BF* h0bd     = (BF*)alloc(2ull * 16384 * 2);
    BF* h1bd     = (BF*)alloc(2ull * 16384 * 2);
    float* c0d   = (float*)alloc(16384ull * 4);
    float* c1d   = (float*)alloc(16384ull * 4);
    unsigned* encFlags = (unsigned*)alloc(64 * 32 * 4);   // 64 blocks x 128B

    hipMemsetAsync(encFlags, 0, 64 * 32 * 4, stream);
    hipMemsetAsync(h0b_e, 0, 2 * 16384 * 2, stream);
    hipMemsetAsync(h1b_e, 0, 2 * 16384 * 2, stream);
    hipMemsetAsync(c0e, 0, 16384 * 4, stream);
    hipMemsetAsync(c1e, 0, 16384 * 4, stream);

    // embeddings
    k_embed_src<<<4096, 256, 0, stream>>>(src_tok, src_emb, x_srcb);
    k_embed_tgt<<<2016, 256, 0, stream>>>(tgt_tok, tgt_emb, embtb, Xout);

    // fused small-weight transposes (one launch)
    TD10 td;
    td.s[0] = eWhh0;              td.d[0] = eWhh0T;  td.K[0] = 512; td.N[0] = 2048;
    td.s[1] = eWih1;              td.d[1] = eWih1T;  td.K[1] = 512; td.N[1] = 2048;
    td.s[2] = eWhh1;              td.d[2] = eWhh1T;  td.K[2] = 512; td.N[2] = 2048;
    td.s[3] = dWih0 + 256 * 2048; td.d[3] = dWih0wT; td.K[3] = 512; td.N[3] = 2048;
    td.s[4] = dWhh0;              td.d[4] = dWhh0T;  td.K[4] = 512; td.N[4] = 2048;
    td.s[5] = dWih1;              td.d[5] = dWih1T;  td.K[5] = 512; td.N[5] = 2048;
    td.s[6] = dWhh1;              td.d[6] = dWhh1T;  td.K[6] = 512; td.N[6] = 2048;
    td.s[7] = eWih0;              td.d[7] = eWih0T;  td.K[7] = 256; td.N[7] = 2048;
    td.s[8] = dWih0;              td.d[8] = dWih0eT; td.K[8] = 256; td.N[8] = 2048;
    td.s[9] = attn_W + 512 * 512; td.d[9] = WeT;     td.K[9] = 512; td.N[9] = 512;
    k_transpose_multi<<<dim3(1024, 10), 256, 0, stream>>>(td);
    k_transpose_bf16<<<dim3(1000, 40), 256, 0, stream>>>(out_W, Wt, 1280, 32000);

    // input-side GEMMs (bf16 out)
    k_mfma<<<dim3(16, 32), 256, 0, stream>>>(x_srcb, eWih0T, eb0, nullptr, X0b, 4096, 2048, 256);
    k_mfma<<<dim3(16, 16), 256, 0, stream>>>(embtb, dWih0eT, db0, nullptr, Xembb, 2016, 2048, 256);
    k_bos<<<dim3(125, 32), 256, 0, stream>>>(out);

    // persistent encoder (decoupled layer pipelines)
    k_enc_persist<<<64, 256, 0, stream>>>(X0b, eWhh0T, eWih1T, eWhh1T, eb1,
                                          h0b_e, h1b_e, h0f_e, h1f_e, c0e, c1e,
                                          ys0b, enc_outb, encFlags);

    // enc_proj = enc_out @ We (bf16 out)
    k_mfma<<<dim3(4, 32), 256, 0, stream>>>(enc_outb, WeT, nullptr, nullptr, enc_projb, 4096, 512, 512);

    k_init_dec<<<64, 256, 0, stream>>>(h0f_e, h1f_e, c0e, c1e,
                                       h0fd, h1fd, h0bd, h1bd, c0d, c1d);

    // decoder: 3 stream launches per step
    for (int t = 0; t < TD; ++t) {
        int cur = t & 1, nxt = cur ^ 1;
        BF* XoutT = Xout + (size_t)t * 32 * KOUT;
        k_dattn2<<<32, 256, 0, stream>>>(enc_projb, enc_outb, src_tok, v_w,
                                         attn_W, attn_b, coal_w, coal_b,
                                         h0fd + cur * 16384, h1fd + cur * 16384,
                                         wctxb, XoutT);
        k_rec<<<32, 256, 0, stream>>>(wctxb, dWih0wT,
                                      h0bd + cur * 16384, dWhh0T,
                                      Xembb + (size_t)t * 32 * 2048, nullptr,
                                      c0d, h0fd + nxt * 16384, h0bd + nxt * 16384,
                                      nullptr, 0);
        k_rec<<<32, 256, 0, stream>>>(h0bd + nxt * 16384, dWih1T,
                                      h1bd + cur * 16384, dWhh1T,
                                      nullptr, db1,
                                      c1d, h1fd + nxt * 16384, h1bd + nxt * 16384,
                                      XoutT, KOUT);
    }

    k_finalize<<<64, 256, 0, stream>>>(h0fd + (TD & 1) * 16384, h1fd + (TD & 1) * 16384,
                                       c0d, c1d, out);
    k_logits<<<dim3(250, 16), 256, 0, stream>>>(Xout, Wt, out_b, out);
}